// Round 1
// baseline (2091.468 us; speedup 1.0000x reference)
//
#include <hip/hip_runtime.h>
#include <math.h>

#define NB_TOK 16384
#define DM     1024
#define NEXP   8
#define KIN    1536

#define BM   128
#define BN   128
#define BKS  16
#define PADF 4
#define LDSROW (BM + PADF)   // 132 floats = 528B rows, 16B-aligned

__device__ __forceinline__ float gelu_f(float x) {
    return 0.5f * x * (1.0f + erff(x * 0.70710678118654752440f));
}

// h = gelu(concat(f0,f1,f2) @ Ws + bs)   (16384 x 1536) @ (1536 x 1024)
__global__ __launch_bounds__(256) void k_shared_gemm(
    const float* __restrict__ f0, const float* __restrict__ f1,
    const float* __restrict__ f2, const float* __restrict__ Ws,
    const float* __restrict__ bs, float* __restrict__ h)
{
    __shared__ float As[BKS][LDSROW];   // transposed: As[k][m]
    __shared__ float Bs[BKS][LDSROW];   // Bs[k][n]
    const int t  = threadIdx.x;
    const int bn = blockIdx.x;          // 0..7
    const int bm = blockIdx.y;          // 0..127
    const int ty = t >> 4, tx = t & 15;
    const int arow = t >> 2;            // 0..63
    const int acol = (t & 3) << 2;      // 0,4,8,12
    const int brow = t >> 5;            // 0..7
    const int bcol = (t & 31) << 2;     // 0..124

    float acc[8][8];
#pragma unroll
    for (int i = 0; i < 8; ++i)
#pragma unroll
        for (int j = 0; j < 8; ++j) acc[i][j] = 0.f;

    for (int k0 = 0; k0 < KIN; k0 += BKS) {
        const int gc = k0 + acol;       // whole BK-tile lives in one source tensor
        const float* src; int ld; int c;
        if (gc < 768)       { src = f0; ld = 768; c = gc; }
        else if (gc < 1280) { src = f1; ld = 512; c = gc - 768; }
        else                { src = f2; ld = 256; c = gc - 1280; }
        const float4 va0 = *(const float4*)(src + (size_t)(bm * BM + arow) * ld + c);
        const float4 va1 = *(const float4*)(src + (size_t)(bm * BM + arow + 64) * ld + c);
        const float4 vb0 = *(const float4*)(Ws + (size_t)(k0 + brow) * DM + bn * BN + bcol);
        const float4 vb1 = *(const float4*)(Ws + (size_t)(k0 + brow + 8) * DM + bn * BN + bcol);
        __syncthreads();
        As[acol + 0][arow] = va0.x; As[acol + 1][arow] = va0.y;
        As[acol + 2][arow] = va0.z; As[acol + 3][arow] = va0.w;
        As[acol + 0][arow + 64] = va1.x; As[acol + 1][arow + 64] = va1.y;
        As[acol + 2][arow + 64] = va1.z; As[acol + 3][arow + 64] = va1.w;
        *(float4*)&Bs[brow][bcol]     = vb0;
        *(float4*)&Bs[brow + 8][bcol] = vb1;
        __syncthreads();
#pragma unroll
        for (int kk = 0; kk < BKS; ++kk) {
            float a[8], b[8];
            *(float4*)&a[0] = *(const float4*)&As[kk][ty * 8];
            *(float4*)&a[4] = *(const float4*)&As[kk][ty * 8 + 4];
            *(float4*)&b[0] = *(const float4*)&Bs[kk][tx * 8];
            *(float4*)&b[4] = *(const float4*)&Bs[kk][tx * 8 + 4];
#pragma unroll
            for (int i = 0; i < 8; ++i)
#pragma unroll
                for (int j = 0; j < 8; ++j)
                    acc[i][j] = fmaf(a[i], b[j], acc[i][j]);
        }
    }
    const int m0 = bm * BM + ty * 8;
    const int n0 = bn * BN + tx * 8;
#pragma unroll
    for (int i = 0; i < 8; ++i) {
        float o[8];
#pragma unroll
        for (int j = 0; j < 8; ++j) o[j] = gelu_f(acc[i][j] + bs[n0 + j]);
        *(float4*)(h + (size_t)(m0 + i) * DM + n0)     = *(float4*)&o[0];
        *(float4*)(h + (size_t)(m0 + i) * DM + n0 + 4) = *(float4*)&o[4];
    }
}

// per-token: logits = h@Wg + bg, softmax, top-2, scatter into per-expert buckets
__global__ __launch_bounds__(256) void k_gate(
    const float* __restrict__ h, const float* __restrict__ Wg,
    const float* __restrict__ bg, int* __restrict__ counts,
    int* __restrict__ btok, float* __restrict__ bwgt)
{
    const int lane = threadIdx.x & 63;
    const int wv   = threadIdx.x >> 6;
    const int tok  = blockIdx.x * 4 + wv;
    const float* hr = h + (size_t)tok * DM;
    float acc[NEXP];
#pragma unroll
    for (int e = 0; e < NEXP; ++e) acc[e] = 0.f;
    for (int j = 0; j < DM / 64; ++j) {
        const float hv = hr[lane + 64 * j];
        const float* wr = Wg + (size_t)(lane + 64 * j) * NEXP;
#pragma unroll
        for (int e = 0; e < NEXP; ++e) acc[e] = fmaf(hv, wr[e], acc[e]);
    }
#pragma unroll
    for (int off = 32; off > 0; off >>= 1) {
#pragma unroll
        for (int e = 0; e < NEXP; ++e) acc[e] += __shfl_xor(acc[e], off, 64);
    }
    if (lane == 0) {
        float lg[NEXP];
        float mx = -1e30f;
#pragma unroll
        for (int e = 0; e < NEXP; ++e) { lg[e] = acc[e] + bg[e]; mx = fmaxf(mx, lg[e]); }
        float p[NEXP]; float s = 0.f;
#pragma unroll
        for (int e = 0; e < NEXP; ++e) { p[e] = expf(lg[e] - mx); s += p[e]; }
        const float inv = 1.f / s;
        int i0 = 0;
#pragma unroll
        for (int e = 1; e < NEXP; ++e) if (p[e] > p[i0]) i0 = e;   // strict > : lowest idx on tie
        int i1 = (i0 == 0) ? 1 : 0;
#pragma unroll
        for (int e = 0; e < NEXP; ++e) if (e != i0 && p[e] > p[i1]) i1 = e;
        const int pos0 = atomicAdd(&counts[i0], 1);
        btok[i0 * NB_TOK + pos0] = tok;  bwgt[i0 * NB_TOK + pos0] = p[i0] * inv;
        const int pos1 = atomicAdd(&counts[i1], 1);
        btok[i1 * NB_TOK + pos1] = tok;  bwgt[i1 * NB_TOK + pos1] = p[i1] * inv;
    }
}

// per expert: gathered rows of h @ We[e], weighted gelu, atomicAdd into out
__global__ __launch_bounds__(256) void k_expert_gemm(
    const float* __restrict__ h, const float* __restrict__ Wexp,
    const float* __restrict__ bexp, const int* __restrict__ counts,
    const int* __restrict__ btok, const float* __restrict__ bwgt,
    float* __restrict__ out)
{
    const int e    = blockIdx.z;
    const int cnt  = counts[e];
    const int row0 = blockIdx.y * BM;
    if (row0 >= cnt) return;
    __shared__ float As[BKS][LDSROW];
    __shared__ float Bs[BKS][LDSROW];
    __shared__ int   sTok[BM];
    __shared__ float sWt[BM];
    const int t = threadIdx.x;
    if (t < BM) {
        const int idx = row0 + t;
        if (idx < cnt) { sTok[t] = btok[e * NB_TOK + idx]; sWt[t] = bwgt[e * NB_TOK + idx]; }
        else           { sTok[t] = -1;                     sWt[t] = 0.f; }
    }
    __syncthreads();
    const float* W = Wexp + (size_t)e * DM * DM;
    const int ty = t >> 4, tx = t & 15;
    const int arow = t >> 2;
    const int acol = (t & 3) << 2;
    const int brow = t >> 5;
    const int bcol = (t & 31) << 2;
    const int tok0 = sTok[arow];
    const int tok1 = sTok[arow + 64];

    float acc[8][8];
#pragma unroll
    for (int i = 0; i < 8; ++i)
#pragma unroll
        for (int j = 0; j < 8; ++j) acc[i][j] = 0.f;

    for (int k0 = 0; k0 < DM; k0 += BKS) {
        float4 va0 = make_float4(0.f, 0.f, 0.f, 0.f);
        float4 va1 = make_float4(0.f, 0.f, 0.f, 0.f);
        if (tok0 >= 0) va0 = *(const float4*)(h + (size_t)tok0 * DM + k0 + acol);
        if (tok1 >= 0) va1 = *(const float4*)(h + (size_t)tok1 * DM + k0 + acol);
        const float4 vb0 = *(const float4*)(W + (size_t)(k0 + brow) * DM + blockIdx.x * BN + bcol);
        const float4 vb1 = *(const float4*)(W + (size_t)(k0 + brow + 8) * DM + blockIdx.x * BN + bcol);
        __syncthreads();
        As[acol + 0][arow] = va0.x; As[acol + 1][arow] = va0.y;
        As[acol + 2][arow] = va0.z; As[acol + 3][arow] = va0.w;
        As[acol + 0][arow + 64] = va1.x; As[acol + 1][arow + 64] = va1.y;
        As[acol + 2][arow + 64] = va1.z; As[acol + 3][arow + 64] = va1.w;
        *(float4*)&Bs[brow][bcol]     = vb0;
        *(float4*)&Bs[brow + 8][bcol] = vb1;
        __syncthreads();
#pragma unroll
        for (int kk = 0; kk < BKS; ++kk) {
            float a[8], b[8];
            *(float4*)&a[0] = *(const float4*)&As[kk][ty * 8];
            *(float4*)&a[4] = *(const float4*)&As[kk][ty * 8 + 4];
            *(float4*)&b[0] = *(const float4*)&Bs[kk][tx * 8];
            *(float4*)&b[4] = *(const float4*)&Bs[kk][tx * 8 + 4];
#pragma unroll
            for (int i = 0; i < 8; ++i)
#pragma unroll
                for (int j = 0; j < 8; ++j)
                    acc[i][j] = fmaf(a[i], b[j], acc[i][j]);
        }
    }
    const int n0 = blockIdx.x * BN + tx * 8;
    const float* be = bexp + (size_t)e * DM;
#pragma unroll
    for (int i = 0; i < 8; ++i) {
        const int r   = ty * 8 + i;
        const int tok = sTok[r];
        if (tok < 0) continue;
        const float w = sWt[r];
#pragma unroll
        for (int j = 0; j < 8; ++j) {
            const float v = gelu_f(acc[i][j] + be[n0 + j]) * w;
            atomicAdd(out + (size_t)tok * DM + n0 + j, v);
        }
    }
}

extern "C" void kernel_launch(void* const* d_in, const int* in_sizes, int n_in,
                              void* d_out, int out_size, void* d_ws, size_t ws_size,
                              hipStream_t stream)
{
    const float* f0 = (const float*)d_in[0];
    const float* f1 = (const float*)d_in[1];
    const float* f2 = (const float*)d_in[2];
    const float* Ws = (const float*)d_in[3];
    const float* bs = (const float*)d_in[4];
    const float* Wg = (const float*)d_in[5];
    const float* bg = (const float*)d_in[6];
    const float* We = (const float*)d_in[7];
    const float* be = (const float*)d_in[8];
    float* out = (float*)d_out;

    // ws layout: h (64MB) | counts (16 ints) | btok (E*B ints) | bwgt (E*B floats)  ~68.2MB
    float* h      = (float*)d_ws;
    int*   counts = (int*)(h + (size_t)NB_TOK * DM);
    int*   btok   = counts + 16;
    float* bwgt   = (float*)(btok + NEXP * NB_TOK);

    hipMemsetAsync(d_out, 0, (size_t)NB_TOK * DM * sizeof(float), stream);
    hipMemsetAsync(counts, 0, 16 * sizeof(int), stream);

    k_shared_gemm<<<dim3(DM / BN, NB_TOK / BM), 256, 0, stream>>>(f0, f1, f2, Ws, bs, h);
    k_gate<<<NB_TOK / 4, 256, 0, stream>>>(h, Wg, bg, counts, btok, bwgt);
    k_expert_gemm<<<dim3(DM / BN, NB_TOK / BM, NEXP), 256, 0, stream>>>(h, We, be, counts, btok, bwgt, out);
}

// Round 3
// 1331.037 us; speedup vs baseline: 1.5713x; 1.5713x over previous
//
#include <hip/hip_runtime.h>
#include <math.h>

#define NB_TOK 16384
#define DM     1024
#define NEXP   8
#define KIN    1536

#define BM   128
#define BN   128
#define BKS  16
#define PADF 4
#define LDSROW (BM + PADF)   // 132 floats

typedef __attribute__((ext_vector_type(8))) short    short8;
typedef __attribute__((ext_vector_type(8))) unsigned short ushort8;
typedef __attribute__((ext_vector_type(4))) float    floatx4;

#define AS1U(p) ((const __attribute__((address_space(1))) unsigned int*)(p))
#define AS3U(p) ((__attribute__((address_space(3))) unsigned int*)(p))

__device__ __forceinline__ float gelu_f(float x) {
    return 0.5f * x * (1.0f + erff(x * 0.70710678118654752440f));
}

__device__ __forceinline__ unsigned short f2bf(float x) {
    unsigned u = __float_as_uint(x);
    u = (u + 0x7FFF + ((u >> 16) & 1)) >> 16;   // RNE
    return (unsigned short)u;
}

// ---------------- shared GEMM: h = gelu(concat @ Ws + bs), fp32 exact ----------------
__global__ __launch_bounds__(256) void k_shared_gemm(
    const float* __restrict__ f0, const float* __restrict__ f1,
    const float* __restrict__ f2, const float* __restrict__ Ws,
    const float* __restrict__ bs, float* __restrict__ h,
    unsigned short* __restrict__ hbf)
{
    __shared__ float As[BKS][LDSROW];
    __shared__ float Bs[BKS][LDSROW];
    const int t  = threadIdx.x;
    const int bn = blockIdx.x;
    const int bm = blockIdx.y;
    const int ty = t >> 4, tx = t & 15;
    const int arow = t >> 2;
    const int acol = (t & 3) << 2;
    const int brow = t >> 5;
    const int bcol = (t & 31) << 2;

    float acc[8][8];
#pragma unroll
    for (int i = 0; i < 8; ++i)
#pragma unroll
        for (int j = 0; j < 8; ++j) acc[i][j] = 0.f;

    for (int k0 = 0; k0 < KIN; k0 += BKS) {
        const int gc = k0 + acol;
        const float* src; int ld; int c;
        if (gc < 768)       { src = f0; ld = 768; c = gc; }
        else if (gc < 1280) { src = f1; ld = 512; c = gc - 768; }
        else                { src = f2; ld = 256; c = gc - 1280; }
        const float4 va0 = *(const float4*)(src + (size_t)(bm * BM + arow) * ld + c);
        const float4 va1 = *(const float4*)(src + (size_t)(bm * BM + arow + 64) * ld + c);
        const float4 vb0 = *(const float4*)(Ws + (size_t)(k0 + brow) * DM + bn * BN + bcol);
        const float4 vb1 = *(const float4*)(Ws + (size_t)(k0 + brow + 8) * DM + bn * BN + bcol);
        __syncthreads();
        As[acol + 0][arow] = va0.x; As[acol + 1][arow] = va0.y;
        As[acol + 2][arow] = va0.z; As[acol + 3][arow] = va0.w;
        As[acol + 0][arow + 64] = va1.x; As[acol + 1][arow + 64] = va1.y;
        As[acol + 2][arow + 64] = va1.z; As[acol + 3][arow + 64] = va1.w;
        *(float4*)&Bs[brow][bcol]     = vb0;
        *(float4*)&Bs[brow + 8][bcol] = vb1;
        __syncthreads();
#pragma unroll
        for (int kk = 0; kk < BKS; ++kk) {
            float a[8], b[8];
            *(float4*)&a[0] = *(const float4*)&As[kk][ty * 8];
            *(float4*)&a[4] = *(const float4*)&As[kk][ty * 8 + 4];
            *(float4*)&b[0] = *(const float4*)&Bs[kk][tx * 8];
            *(float4*)&b[4] = *(const float4*)&Bs[kk][tx * 8 + 4];
#pragma unroll
            for (int i = 0; i < 8; ++i)
#pragma unroll
                for (int j = 0; j < 8; ++j)
                    acc[i][j] = fmaf(a[i], b[j], acc[i][j]);
        }
    }
    const int m0 = bm * BM + ty * 8;
    const int n0 = bn * BN + tx * 8;
#pragma unroll
    for (int i = 0; i < 8; ++i) {
        float o[8];
#pragma unroll
        for (int j = 0; j < 8; ++j) o[j] = gelu_f(acc[i][j] + bs[n0 + j]);
        *(float4*)(h + (size_t)(m0 + i) * DM + n0)     = *(float4*)&o[0];
        *(float4*)(h + (size_t)(m0 + i) * DM + n0 + 4) = *(float4*)&o[4];
        ushort8 hb;
#pragma unroll
        for (int j = 0; j < 8; ++j) hb[j] = f2bf(o[j]);
        *(ushort8*)(hbf + (size_t)(m0 + i) * DM + n0) = hb;
    }
}

// ---------------- W_experts fp32 [e][k][n] -> bf16 transposed [e][n][k] ----------------
__global__ __launch_bounds__(256) void k_wt_bf16(
    const float* __restrict__ We, unsigned short* __restrict__ WeT)
{
    __shared__ float s[32][33];
    const int e  = blockIdx.z;
    const int k0 = blockIdx.y * 32, n0 = blockIdx.x * 32;
    const int c  = threadIdx.x & 31, r = threadIdx.x >> 5;   // 8 rows/pass
    const float* W = We + ((size_t)e << 20);
#pragma unroll
    for (int p = 0; p < 4; ++p) {
        const int k = r + p * 8;
        s[k][c] = W[(size_t)(k0 + k) * DM + n0 + c];
    }
    __syncthreads();
#pragma unroll
    for (int p = 0; p < 4; ++p) {
        const int n = r + p * 8;
        WeT[((size_t)e << 20) + (size_t)(n0 + n) * DM + k0 + c] = f2bf(s[c][n]);
    }
}

// ---------------- gate: fp32 exact, top-2, bucket scatter ----------------
__global__ __launch_bounds__(256) void k_gate(
    const float* __restrict__ h, const float* __restrict__ Wg,
    const float* __restrict__ bg, int* __restrict__ counts,
    int* __restrict__ btok, float* __restrict__ bwgt)
{
    const int lane = threadIdx.x & 63;
    const int wv   = threadIdx.x >> 6;
    const int tok  = blockIdx.x * 4 + wv;
    const float* hr = h + (size_t)tok * DM;
    float acc[NEXP];
#pragma unroll
    for (int e = 0; e < NEXP; ++e) acc[e] = 0.f;
    for (int j = 0; j < DM / 64; ++j) {
        const float hv = hr[lane + 64 * j];
        const float* wr = Wg + (size_t)(lane + 64 * j) * NEXP;
#pragma unroll
        for (int e = 0; e < NEXP; ++e) acc[e] = fmaf(hv, wr[e], acc[e]);
    }
#pragma unroll
    for (int off = 32; off > 0; off >>= 1) {
#pragma unroll
        for (int e = 0; e < NEXP; ++e) acc[e] += __shfl_xor(acc[e], off, 64);
    }
    if (lane == 0) {
        float lg[NEXP];
        float mx = -1e30f;
#pragma unroll
        for (int e = 0; e < NEXP; ++e) { lg[e] = acc[e] + bg[e]; mx = fmaxf(mx, lg[e]); }
        float p[NEXP]; float s = 0.f;
#pragma unroll
        for (int e = 0; e < NEXP; ++e) { p[e] = expf(lg[e] - mx); s += p[e]; }
        const float inv = 1.f / s;
        int i0 = 0;
#pragma unroll
        for (int e = 1; e < NEXP; ++e) if (p[e] > p[i0]) i0 = e;
        int i1 = (i0 == 0) ? 1 : 0;
#pragma unroll
        for (int e = 0; e < NEXP; ++e) if (e != i0 && p[e] > p[i1]) i1 = e;
        const int pos0 = atomicAdd(&counts[i0], 1);
        btok[i0 * NB_TOK + pos0] = tok;  bwgt[i0 * NB_TOK + pos0] = p[i0] * inv;
        const int pos1 = atomicAdd(&counts[i1], 1);
        btok[i1 * NB_TOK + pos1] = tok;  bwgt[i1 * NB_TOK + pos1] = p[i1] * inv;
    }
}

// ---------------- expert GEMM: bf16 MFMA, gathered rows, atomic epilogue ----------------
// tile 128x128, BK=64, 4 waves (2x2 of 64x64), global_load_lds + chunk-XOR swizzle
__global__ __launch_bounds__(256) void k_expert_mfma(
    const unsigned short* __restrict__ hbf,   // [B][DM] bf16
    const unsigned short* __restrict__ WeT,   // [E][n][k] bf16
    const float* __restrict__ bexp,
    const int* __restrict__ counts,
    const int* __restrict__ btok, const float* __restrict__ bwgt,
    float* __restrict__ out)
{
    const int e    = blockIdx.z;
    const int cnt  = counts[e];
    const int row0 = blockIdx.y * 128;
    if (row0 >= cnt) return;

    __shared__ unsigned short ldsA[128][64];   // [row][k] swizzled 16B-chunks, 16KB
    __shared__ unsigned short ldsB[128][64];   // [n][k]  swizzled, 16KB
    __shared__ int   sTok[128];
    __shared__ float sWt[128];

    const int t    = threadIdx.x;
    const int lane = t & 63;
    const int wave = t >> 6;

    if (t < 128) {
        const int idx = row0 + t;
        if (idx < cnt) { sTok[t] = btok[e * NB_TOK + idx]; sWt[t] = bwgt[e * NB_TOK + idx]; }
        else           { sTok[t] = -1;                     sWt[t] = 0.f; }
    }
    __syncthreads();

    // staging source pointers: row = q*32 + (t>>3); chunk = t&7
    // swizzle: source k-chunk g = (t&7) ^ ((t>>3)&7)
    const int srow = t >> 3;                    // 0..31
    const int g    = (t & 7) ^ (srow & 7);
    const int n0g  = blockIdx.x * 128;
    const unsigned short* srcA[4];
    const unsigned short* srcB[4];
#pragma unroll
    for (int q = 0; q < 4; ++q) {
        int tk = sTok[q * 32 + srow];
        if (tk < 0) tk = 0;                     // safe address; result discarded
        srcA[q] = hbf + (size_t)tk * DM + g * 8;
        srcB[q] = WeT + ((size_t)e << 20) + (size_t)(n0g + q * 32 + srow) * DM + g * 8;
    }

    // ds_read offsets (bytes): row*128 + ((c ^ (row&7))<<4), c = ks*4 + (lane>>4)
    const int grp = lane >> 4;
    int offA[2][4], offB[2][4];
#pragma unroll
    for (int ks = 0; ks < 2; ++ks)
#pragma unroll
        for (int m = 0; m < 4; ++m) {
            const int rA = ((wave >> 1) * 64) + m * 16 + (lane & 15);
            const int rB = ((wave & 1) * 64) + m * 16 + (lane & 15);
            const int c  = ks * 4 + grp;
            offA[ks][m] = rA * 128 + (((c ^ (rA & 7)) & 7) << 4);
            offB[ks][m] = rB * 128 + (((c ^ (rB & 7)) & 7) << 4);
        }

    floatx4 acc[4][4];
#pragma unroll
    for (int m = 0; m < 4; ++m)
#pragma unroll
        for (int n = 0; n < 4; ++n) acc[m][n] = (floatx4){0.f, 0.f, 0.f, 0.f};

    const char* lA = (const char*)&ldsA[0][0];
    const char* lB = (const char*)&ldsB[0][0];
    char* lAw = (char*)&ldsA[0][0];
    char* lBw = (char*)&ldsB[0][0];

    for (int kt = 0; kt < DM / 64; ++kt) {
        const int k0 = kt * 64;
        __syncthreads();   // prior reads done before overwrite
#pragma unroll
        for (int q = 0; q < 4; ++q) {
            __builtin_amdgcn_global_load_lds(AS1U(srcA[q] + k0), AS3U(lAw + q * 4096 + wave * 1024), 16, 0, 0);
            __builtin_amdgcn_global_load_lds(AS1U(srcB[q] + k0), AS3U(lBw + q * 4096 + wave * 1024), 16, 0, 0);
        }
        __syncthreads();   // drains vmcnt before use
#pragma unroll
        for (int ks = 0; ks < 2; ++ks) {
            short8 av[4], bv[4];
#pragma unroll
            for (int m = 0; m < 4; ++m) av[m] = *(const short8*)(lA + offA[ks][m]);
#pragma unroll
            for (int n = 0; n < 4; ++n) bv[n] = *(const short8*)(lB + offB[ks][n]);
#pragma unroll
            for (int m = 0; m < 4; ++m)
#pragma unroll
                for (int n = 0; n < 4; ++n)
                    acc[m][n] = __builtin_amdgcn_mfma_f32_16x16x32_bf16(av[m], bv[n], acc[m][n], 0, 0, 0);
        }
    }

    // epilogue: gelu(acc + bias) * w, atomicAdd into out
    const int wr = wave >> 1, wc = wave & 1;
#pragma unroll
    for (int n = 0; n < 4; ++n) {
        const int col  = n0g + wc * 64 + n * 16 + (lane & 15);
        const float bias = bexp[e * DM + col];
#pragma unroll
        for (int m = 0; m < 4; ++m) {
            const int rbase = wr * 64 + m * 16 + (lane >> 4) * 4;
#pragma unroll
            for (int reg = 0; reg < 4; ++reg) {
                const int r   = rbase + reg;
                const int tok = sTok[r];
                if (tok < 0) continue;
                const float v = gelu_f(acc[m][n][reg] + bias) * sWt[r];
                atomicAdd(out + (size_t)tok * DM + col, v);
            }
        }
    }
}

extern "C" void kernel_launch(void* const* d_in, const int* in_sizes, int n_in,
                              void* d_out, int out_size, void* d_ws, size_t ws_size,
                              hipStream_t stream)
{
    const float* f0 = (const float*)d_in[0];
    const float* f1 = (const float*)d_in[1];
    const float* f2 = (const float*)d_in[2];
    const float* Ws = (const float*)d_in[3];
    const float* bs = (const float*)d_in[4];
    const float* Wg = (const float*)d_in[5];
    const float* bg = (const float*)d_in[6];
    const float* We = (const float*)d_in[7];
    const float* be = (const float*)d_in[8];
    float* out = (float*)d_out;

    // ws: h f32 (64MB) | hbf (32MB) | WeT (16MB) | counts | btok | bwgt  ~ 118MB
    char* base = (char*)d_ws;
    float*          h      = (float*)base;
    unsigned short* hbf    = (unsigned short*)(base + 67108864);
    unsigned short* WeT    = (unsigned short*)(base + 100663296);
    int*            counts = (int*)(base + 117440512);
    int*            btok   = counts + 16;
    float*          bwgt   = (float*)(btok + NEXP * NB_TOK);

    hipMemsetAsync(d_out, 0, (size_t)NB_TOK * DM * sizeof(float), stream);
    hipMemsetAsync(counts, 0, 16 * sizeof(int), stream);

    k_wt_bf16<<<dim3(DM / 32, DM / 32, NEXP), 256, 0, stream>>>(We, WeT);
    k_shared_gemm<<<dim3(DM / BN, NB_TOK / BM), 256, 0, stream>>>(f0, f1, f2, Ws, bs, h, hbf);
    k_gate<<<NB_TOK / 4, 256, 0, stream>>>(h, Wg, bg, counts, btok, bwgt);
    k_expert_mfma<<<dim3(DM / 128, NB_TOK / 128, NEXP), 256, 0, stream>>>(hbf, WeT, be, counts, btok, bwgt, out);
}

// Round 4
// 877.450 us; speedup vs baseline: 2.3836x; 1.5169x over previous
//
#include <hip/hip_runtime.h>
#include <math.h>

#define NB_TOK 16384
#define DM     1024
#define NEXP   8
#define KIN    1536

#define BM   128
#define BN   128
#define BKS  16
#define PADF 4
#define LDSROW (BM + PADF)

typedef __attribute__((ext_vector_type(8))) short          short8;
typedef __attribute__((ext_vector_type(8))) unsigned short ushort8;
typedef __attribute__((ext_vector_type(4))) unsigned short ushort4v;
typedef __attribute__((ext_vector_type(8))) _Float16       half8;
typedef __attribute__((ext_vector_type(4))) float          floatx4;

#define AS1U(p) ((const __attribute__((address_space(1))) unsigned int*)(p))
#define AS3U(p) ((__attribute__((address_space(3))) unsigned int*)(p))

__device__ __forceinline__ float gelu_f(float x) {
    return 0.5f * x * (1.0f + erff(x * 0.70710678118654752440f));
}

__device__ __forceinline__ unsigned short f2bf(float x) {
    unsigned u = __float_as_uint(x);
    u = (u + 0x7FFF + ((u >> 16) & 1)) >> 16;   // RNE
    return (unsigned short)u;
}

__device__ __forceinline__ void split_h16(float x, unsigned short& hi, unsigned short& lo) {
    _Float16 h = (_Float16)x;
    float r = x - (float)h;
    _Float16 l = (_Float16)r;
    hi = *(unsigned short*)&h;
    lo = *(unsigned short*)&l;
}

// ---------------- feature split: concat fp32 -> fp16 hi/lo [tok][KIN], A scaled x4 ----------------
__global__ __launch_bounds__(256) void k_splitA(
    const float* __restrict__ f0, const float* __restrict__ f1,
    const float* __restrict__ f2, unsigned short* __restrict__ Ah,
    unsigned short* __restrict__ Al)
{
    const int i4  = blockIdx.x * 256 + threadIdx.x;   // quad index
    const int tok = i4 / (KIN / 4);
    const int k   = (i4 % (KIN / 4)) * 4;
    const float* src; int ld, c;
    if (k < 768)       { src = f0; ld = 768; c = k; }
    else if (k < 1280) { src = f1; ld = 512; c = k - 768; }
    else               { src = f2; ld = 256; c = k - 1280; }
    const float4 v = *(const float4*)(src + (size_t)tok * ld + c);
    const float* vp = (const float*)&v;
    ushort4v hi, lo;
#pragma unroll
    for (int j = 0; j < 4; ++j) {
        unsigned short h, l;
        split_h16(vp[j] * 4.0f, h, l);
        hi[j] = h; lo[j] = l;
    }
    *(ushort4v*)(Ah + (size_t)tok * KIN + k) = hi;
    *(ushort4v*)(Al + (size_t)tok * KIN + k) = lo;
}

// ---------------- Ws fp32 [k][n] -> fp16 hi/lo transposed [n][k], scaled x256 ----------------
__global__ __launch_bounds__(256) void k_splitB(
    const float* __restrict__ Ws, unsigned short* __restrict__ BhT,
    unsigned short* __restrict__ BlT)
{
    __shared__ float s[32][33];
    const int n0 = blockIdx.x * 32, k0 = blockIdx.y * 32;
    const int c  = threadIdx.x & 31, r = threadIdx.x >> 5;
#pragma unroll
    for (int p = 0; p < 4; ++p)
        s[r + p * 8][c] = Ws[(size_t)(k0 + r + p * 8) * DM + n0 + c];
    __syncthreads();
#pragma unroll
    for (int p = 0; p < 4; ++p) {
        const int n = r + p * 8;
        unsigned short h, l;
        split_h16(s[c][n] * 256.0f, h, l);
        BhT[(size_t)(n0 + n) * KIN + k0 + c] = h;
        BlT[(size_t)(n0 + n) * KIN + k0 + c] = l;
    }
}

// ---------------- shared GEMM via fp16x2-split MFMA (3 products = fp32-grade) ----------------
// h = gelu((A4 @ Ws256)/1024 + bs); writes h fp32 + hbf bf16
__global__ __launch_bounds__(256) void k_shared_mfma(
    const unsigned short* __restrict__ Ah, const unsigned short* __restrict__ Al,
    const unsigned short* __restrict__ BhT, const unsigned short* __restrict__ BlT,
    const float* __restrict__ bs, float* __restrict__ h,
    unsigned short* __restrict__ hbf)
{
    __shared__ unsigned short ldsAh[128][64];
    __shared__ unsigned short ldsAl[128][64];
    __shared__ unsigned short ldsBh[128][64];
    __shared__ unsigned short ldsBl[128][64];

    const int t    = threadIdx.x;
    const int lane = t & 63;
    const int wave = t >> 6;
    const int row0 = blockIdx.y * 128;   // token base
    const int n0g  = blockIdx.x * 128;

    const int srow = t >> 3;
    const int g    = (t & 7) ^ (srow & 7);
    const unsigned short *sAh[4], *sAl[4], *sBh[4], *sBl[4];
#pragma unroll
    for (int q = 0; q < 4; ++q) {
        const size_t ra = (size_t)(row0 + q * 32 + srow) * KIN + g * 8;
        const size_t rb = (size_t)(n0g + q * 32 + srow) * KIN + g * 8;
        sAh[q] = Ah + ra; sAl[q] = Al + ra;
        sBh[q] = BhT + rb; sBl[q] = BlT + rb;
    }

    const int grp = lane >> 4;
    int offA[2][4], offB[2][4];
#pragma unroll
    for (int ks = 0; ks < 2; ++ks)
#pragma unroll
        for (int m = 0; m < 4; ++m) {
            const int rA = ((wave >> 1) * 64) + m * 16 + (lane & 15);
            const int rB = ((wave & 1) * 64) + m * 16 + (lane & 15);
            const int c  = ks * 4 + grp;
            offA[ks][m] = rA * 128 + (((c ^ (rA & 7)) & 7) << 4);
            offB[ks][m] = rB * 128 + (((c ^ (rB & 7)) & 7) << 4);
        }

    floatx4 acc[4][4];
#pragma unroll
    for (int m = 0; m < 4; ++m)
#pragma unroll
        for (int n = 0; n < 4; ++n) acc[m][n] = (floatx4){0.f, 0.f, 0.f, 0.f};

    const char* lAh = (const char*)&ldsAh[0][0];
    const char* lAl = (const char*)&ldsAl[0][0];
    const char* lBh = (const char*)&ldsBh[0][0];
    const char* lBl = (const char*)&ldsBl[0][0];

    for (int kt = 0; kt < KIN / 64; ++kt) {
        const int k0 = kt * 64;
        __syncthreads();
#pragma unroll
        for (int q = 0; q < 4; ++q) {
            const int dst = q * 4096 + wave * 1024;
            __builtin_amdgcn_global_load_lds(AS1U(sAh[q] + k0), AS3U((char*)lAh + dst), 16, 0, 0);
            __builtin_amdgcn_global_load_lds(AS1U(sAl[q] + k0), AS3U((char*)lAl + dst), 16, 0, 0);
            __builtin_amdgcn_global_load_lds(AS1U(sBh[q] + k0), AS3U((char*)lBh + dst), 16, 0, 0);
            __builtin_amdgcn_global_load_lds(AS1U(sBl[q] + k0), AS3U((char*)lBl + dst), 16, 0, 0);
        }
        __syncthreads();
#pragma unroll
        for (int ks = 0; ks < 2; ++ks) {
            half8 ah[4], al[4], bh[4], bl[4];
#pragma unroll
            for (int m = 0; m < 4; ++m) {
                ah[m] = *(const half8*)(lAh + offA[ks][m]);
                al[m] = *(const half8*)(lAl + offA[ks][m]);
            }
#pragma unroll
            for (int n = 0; n < 4; ++n) {
                bh[n] = *(const half8*)(lBh + offB[ks][n]);
                bl[n] = *(const half8*)(lBl + offB[ks][n]);
            }
#pragma unroll
            for (int m = 0; m < 4; ++m)
#pragma unroll
                for (int n = 0; n < 4; ++n) {
                    acc[m][n] = __builtin_amdgcn_mfma_f32_16x16x32_f16(ah[m], bh[n], acc[m][n], 0, 0, 0);
                    acc[m][n] = __builtin_amdgcn_mfma_f32_16x16x32_f16(ah[m], bl[n], acc[m][n], 0, 0, 0);
                    acc[m][n] = __builtin_amdgcn_mfma_f32_16x16x32_f16(al[m], bh[n], acc[m][n], 0, 0, 0);
                }
        }
    }

    const int wr = wave >> 1, wc = wave & 1;
#pragma unroll
    for (int n = 0; n < 4; ++n) {
        const int col  = n0g + wc * 64 + n * 16 + (lane & 15);
        const float bias = bs[col];
#pragma unroll
        for (int m = 0; m < 4; ++m) {
            const int rbase = row0 + wr * 64 + m * 16 + (lane >> 4) * 4;
#pragma unroll
            for (int reg = 0; reg < 4; ++reg) {
                const float o = gelu_f(acc[m][n][reg] * (1.0f / 1024.0f) + bias);
                h[(size_t)(rbase + reg) * DM + col]   = o;
                hbf[(size_t)(rbase + reg) * DM + col] = f2bf(o);
            }
        }
    }
}

// ---------------- W_experts fp32 [e][k][n] -> bf16 transposed [e][n][k] ----------------
__global__ __launch_bounds__(256) void k_wt_bf16(
    const float* __restrict__ We, unsigned short* __restrict__ WeT)
{
    __shared__ float s[32][33];
    const int e  = blockIdx.z;
    const int k0 = blockIdx.y * 32, n0 = blockIdx.x * 32;
    const int c  = threadIdx.x & 31, r = threadIdx.x >> 5;
    const float* W = We + ((size_t)e << 20);
#pragma unroll
    for (int p = 0; p < 4; ++p) {
        const int k = r + p * 8;
        s[k][c] = W[(size_t)(k0 + k) * DM + n0 + c];
    }
    __syncthreads();
#pragma unroll
    for (int p = 0; p < 4; ++p) {
        const int n = r + p * 8;
        WeT[((size_t)e << 20) + (size_t)(n0 + n) * DM + k0 + c] = f2bf(s[c][n]);
    }
}

// ---------------- gate: fp32 exact, top-2, bucket scatter ----------------
__global__ __launch_bounds__(256) void k_gate(
    const float* __restrict__ h, const float* __restrict__ Wg,
    const float* __restrict__ bg, int* __restrict__ counts,
    int* __restrict__ btok, float* __restrict__ bwgt)
{
    const int lane = threadIdx.x & 63;
    const int wv   = threadIdx.x >> 6;
    const int tok  = blockIdx.x * 4 + wv;
    const float* hr = h + (size_t)tok * DM;
    float acc[NEXP];
#pragma unroll
    for (int e = 0; e < NEXP; ++e) acc[e] = 0.f;
    for (int j = 0; j < DM / 64; ++j) {
        const float hv = hr[lane + 64 * j];
        const float* wr = Wg + (size_t)(lane + 64 * j) * NEXP;
#pragma unroll
        for (int e = 0; e < NEXP; ++e) acc[e] = fmaf(hv, wr[e], acc[e]);
    }
#pragma unroll
    for (int off = 32; off > 0; off >>= 1) {
#pragma unroll
        for (int e = 0; e < NEXP; ++e) acc[e] += __shfl_xor(acc[e], off, 64);
    }
    if (lane == 0) {
        float lg[NEXP];
        float mx = -1e30f;
#pragma unroll
        for (int e = 0; e < NEXP; ++e) { lg[e] = acc[e] + bg[e]; mx = fmaxf(mx, lg[e]); }
        float p[NEXP]; float s = 0.f;
#pragma unroll
        for (int e = 0; e < NEXP; ++e) { p[e] = expf(lg[e] - mx); s += p[e]; }
        const float inv = 1.f / s;
        int i0 = 0;
#pragma unroll
        for (int e = 1; e < NEXP; ++e) if (p[e] > p[i0]) i0 = e;
        int i1 = (i0 == 0) ? 1 : 0;
#pragma unroll
        for (int e = 0; e < NEXP; ++e) if (e != i0 && p[e] > p[i1]) i1 = e;
        const int pos0 = atomicAdd(&counts[i0], 1);
        btok[i0 * NB_TOK + pos0] = tok;  bwgt[i0 * NB_TOK + pos0] = p[i0] * inv;
        const int pos1 = atomicAdd(&counts[i1], 1);
        btok[i1 * NB_TOK + pos1] = tok;  bwgt[i1 * NB_TOK + pos1] = p[i1] * inv;
    }
}

// ---------------- expert GEMM: bf16 MFMA, gathered rows, atomic epilogue ----------------
__global__ __launch_bounds__(256) void k_expert_mfma(
    const unsigned short* __restrict__ hbf,
    const unsigned short* __restrict__ WeT,
    const float* __restrict__ bexp,
    const int* __restrict__ counts,
    const int* __restrict__ btok, const float* __restrict__ bwgt,
    float* __restrict__ out)
{
    const int e    = blockIdx.z;
    const int cnt  = counts[e];
    const int row0 = blockIdx.y * 128;
    if (row0 >= cnt) return;

    __shared__ unsigned short ldsA[128][64];
    __shared__ unsigned short ldsB[128][64];
    __shared__ int   sTok[128];
    __shared__ float sWt[128];

    const int t    = threadIdx.x;
    const int lane = t & 63;
    const int wave = t >> 6;

    if (t < 128) {
        const int idx = row0 + t;
        if (idx < cnt) { sTok[t] = btok[e * NB_TOK + idx]; sWt[t] = bwgt[e * NB_TOK + idx]; }
        else           { sTok[t] = -1;                     sWt[t] = 0.f; }
    }
    __syncthreads();

    const int srow = t >> 3;
    const int g    = (t & 7) ^ (srow & 7);
    const int n0g  = blockIdx.x * 128;
    const unsigned short* srcA[4];
    const unsigned short* srcB[4];
#pragma unroll
    for (int q = 0; q < 4; ++q) {
        int tk = sTok[q * 32 + srow];
        if (tk < 0) tk = 0;
        srcA[q] = hbf + (size_t)tk * DM + g * 8;
        srcB[q] = WeT + ((size_t)e << 20) + (size_t)(n0g + q * 32 + srow) * DM + g * 8;
    }

    const int grp = lane >> 4;
    int offA[2][4], offB[2][4];
#pragma unroll
    for (int ks = 0; ks < 2; ++ks)
#pragma unroll
        for (int m = 0; m < 4; ++m) {
            const int rA = ((wave >> 1) * 64) + m * 16 + (lane & 15);
            const int rB = ((wave & 1) * 64) + m * 16 + (lane & 15);
            const int c  = ks * 4 + grp;
            offA[ks][m] = rA * 128 + (((c ^ (rA & 7)) & 7) << 4);
            offB[ks][m] = rB * 128 + (((c ^ (rB & 7)) & 7) << 4);
        }

    floatx4 acc[4][4];
#pragma unroll
    for (int m = 0; m < 4; ++m)
#pragma unroll
        for (int n = 0; n < 4; ++n) acc[m][n] = (floatx4){0.f, 0.f, 0.f, 0.f};

    const char* lA = (const char*)&ldsA[0][0];
    const char* lB = (const char*)&ldsB[0][0];
    char* lAw = (char*)&ldsA[0][0];
    char* lBw = (char*)&ldsB[0][0];

    for (int kt = 0; kt < DM / 64; ++kt) {
        const int k0 = kt * 64;
        __syncthreads();
#pragma unroll
        for (int q = 0; q < 4; ++q) {
            __builtin_amdgcn_global_load_lds(AS1U(srcA[q] + k0), AS3U(lAw + q * 4096 + wave * 1024), 16, 0, 0);
            __builtin_amdgcn_global_load_lds(AS1U(srcB[q] + k0), AS3U(lBw + q * 4096 + wave * 1024), 16, 0, 0);
        }
        __syncthreads();
#pragma unroll
        for (int ks = 0; ks < 2; ++ks) {
            short8 av[4], bv[4];
#pragma unroll
            for (int m = 0; m < 4; ++m) av[m] = *(const short8*)(lA + offA[ks][m]);
#pragma unroll
            for (int n = 0; n < 4; ++n) bv[n] = *(const short8*)(lB + offB[ks][n]);
#pragma unroll
            for (int m = 0; m < 4; ++m)
#pragma unroll
                for (int n = 0; n < 4; ++n)
                    acc[m][n] = __builtin_amdgcn_mfma_f32_16x16x32_bf16(av[m], bv[n], acc[m][n], 0, 0, 0);
        }
    }

    const int wr = wave >> 1, wc = wave & 1;
#pragma unroll
    for (int n = 0; n < 4; ++n) {
        const int col  = n0g + wc * 64 + n * 16 + (lane & 15);
        const float bias = bexp[e * DM + col];
#pragma unroll
        for (int m = 0; m < 4; ++m) {
            const int rbase = wr * 64 + m * 16 + (lane >> 4) * 4;
#pragma unroll
            for (int reg = 0; reg < 4; ++reg) {
                const int r   = rbase + reg;
                const int tok = sTok[r];
                if (tok < 0) continue;
                const float v = gelu_f(acc[m][n][reg] + bias) * sWt[r];
                atomicAdd(out + (size_t)tok * DM + col, v);
            }
        }
    }
}

extern "C" void kernel_launch(void* const* d_in, const int* in_sizes, int n_in,
                              void* d_out, int out_size, void* d_ws, size_t ws_size,
                              hipStream_t stream)
{
    const float* f0 = (const float*)d_in[0];
    const float* f1 = (const float*)d_in[1];
    const float* f2 = (const float*)d_in[2];
    const float* Ws = (const float*)d_in[3];
    const float* bs = (const float*)d_in[4];
    const float* Wg = (const float*)d_in[5];
    const float* bg = (const float*)d_in[6];
    const float* We = (const float*)d_in[7];
    const float* be = (const float*)d_in[8];
    float* out = (float*)d_out;

    // ws layout (peak ~198MB):
    //  h      @ 0        (64MB)
    //  hbf    @ 64MB     (32MB)
    //  Ah     @ 96MB     (48MB)   <- WeT (16MB) aliases here after shared gemm
    //  Al     @ 144MB    (48MB)
    //  BhT    @ 192MB    (3MB)    <- gate buckets alias here after shared gemm
    //  BlT    @ 195MB    (3MB)
    char* base = (char*)d_ws;
    float*          h      = (float*)(base);
    unsigned short* hbf    = (unsigned short*)(base + 67108864);
    unsigned short* Ah     = (unsigned short*)(base + 100663296);
    unsigned short* WeT    = (unsigned short*)(base + 100663296);   // alias (after shared)
    unsigned short* Al     = (unsigned short*)(base + 150994944);
    unsigned short* BhT    = (unsigned short*)(base + 201326592);
    unsigned short* BlT    = (unsigned short*)(base + 204472320);
    int*            counts = (int*)(base + 201326592);              // alias BhT (after shared)
    int*            btok   = counts + 16;
    float*          bwgt   = (float*)(btok + NEXP * NB_TOK);

    k_splitA<<<NB_TOK * (KIN / 4) / 256, 256, 0, stream>>>(f0, f1, f2, Ah, Al);
    k_splitB<<<dim3(DM / 32, KIN / 32), 256, 0, stream>>>(Ws, BhT, BlT);
    k_shared_mfma<<<dim3(DM / 128, NB_TOK / 128), 256, 0, stream>>>(Ah, Al, BhT, BlT, bs, h, hbf);

    hipMemsetAsync(counts, 0, 16 * sizeof(int), stream);
    k_gate<<<NB_TOK / 4, 256, 0, stream>>>(h, Wg, bg, counts, btok, bwgt);

    k_wt_bf16<<<dim3(DM / 32, DM / 32, NEXP), 256, 0, stream>>>(We, WeT);

    hipMemsetAsync(d_out, 0, (size_t)NB_TOK * DM * sizeof(float), stream);
    k_expert_mfma<<<dim3(DM / 128, NB_TOK / 128, NEXP), 256, 0, stream>>>(hbf, WeT, be, counts, btok, bwgt, out);
}

// Round 5
// 526.697 us; speedup vs baseline: 3.9709x; 1.6659x over previous
//
#include <hip/hip_runtime.h>
#include <math.h>

#define NB_TOK 16384
#define DM     1024
#define NEXP   8
#define KIN    1536

typedef __attribute__((ext_vector_type(8))) short          short8;
typedef __attribute__((ext_vector_type(8))) unsigned short ushort8;
typedef __attribute__((ext_vector_type(4))) unsigned short ushort4v;
typedef __attribute__((ext_vector_type(8))) _Float16       half8;
typedef __attribute__((ext_vector_type(4))) float          floatx4;

#define AS1U(p) ((const __attribute__((address_space(1))) unsigned int*)(p))
#define AS3U(p) ((__attribute__((address_space(3))) unsigned int*)(p))

__device__ __forceinline__ float gelu_f(float x) {
    return 0.5f * x * (1.0f + erff(x * 0.70710678118654752440f));
}

__device__ __forceinline__ unsigned short f2bf(float x) {
    unsigned u = __float_as_uint(x);
    u = (u + 0x7FFF + ((u >> 16) & 1)) >> 16;   // RNE
    return (unsigned short)u;
}

__device__ __forceinline__ void split_h16(float x, unsigned short& hi, unsigned short& lo) {
    _Float16 h = (_Float16)x;
    float r = x - (float)h;
    _Float16 l = (_Float16)r;
    hi = *(unsigned short*)&h;
    lo = *(unsigned short*)&l;
}

// ---------------- feature split: concat fp32 -> fp16 hi/lo [tok][KIN], A scaled x4 ----------------
__global__ __launch_bounds__(256) void k_splitA(
    const float* __restrict__ f0, const float* __restrict__ f1,
    const float* __restrict__ f2, unsigned short* __restrict__ Ah,
    unsigned short* __restrict__ Al)
{
    const int i4  = blockIdx.x * 256 + threadIdx.x;
    const int tok = i4 / (KIN / 4);
    const int k   = (i4 % (KIN / 4)) * 4;
    const float* src; int ld, c;
    if (k < 768)       { src = f0; ld = 768; c = k; }
    else if (k < 1280) { src = f1; ld = 512; c = k - 768; }
    else               { src = f2; ld = 256; c = k - 1280; }
    const float4 v = *(const float4*)(src + (size_t)tok * ld + c);
    const float* vp = (const float*)&v;
    ushort4v hi, lo;
#pragma unroll
    for (int j = 0; j < 4; ++j) {
        unsigned short h, l;
        split_h16(vp[j] * 4.0f, h, l);
        hi[j] = h; lo[j] = l;
    }
    *(ushort4v*)(Ah + (size_t)tok * KIN + k) = hi;
    *(ushort4v*)(Al + (size_t)tok * KIN + k) = lo;
}

// ---------------- Ws fp32 [k][n] -> fp16 hi/lo transposed [n][k], scaled x256 ----------------
__global__ __launch_bounds__(256) void k_splitB(
    const float* __restrict__ Ws, unsigned short* __restrict__ BhT,
    unsigned short* __restrict__ BlT)
{
    __shared__ float s[32][33];
    const int n0 = blockIdx.x * 32, k0 = blockIdx.y * 32;
    const int c  = threadIdx.x & 31, r = threadIdx.x >> 5;
#pragma unroll
    for (int p = 0; p < 4; ++p)
        s[r + p * 8][c] = Ws[(size_t)(k0 + r + p * 8) * DM + n0 + c];
    __syncthreads();
#pragma unroll
    for (int p = 0; p < 4; ++p) {
        const int n = r + p * 8;
        unsigned short h, l;
        split_h16(s[c][n] * 256.0f, h, l);
        BhT[(size_t)(n0 + n) * KIN + k0 + c] = h;
        BlT[(size_t)(n0 + n) * KIN + k0 + c] = l;
    }
}

// ---------------- shared GEMM via fp16x2-split MFMA (3 products = fp32-grade) ----------------
__global__ __launch_bounds__(256) void k_shared_mfma(
    const unsigned short* __restrict__ Ah, const unsigned short* __restrict__ Al,
    const unsigned short* __restrict__ BhT, const unsigned short* __restrict__ BlT,
    const float* __restrict__ bs, float* __restrict__ h,
    unsigned short* __restrict__ hbf)
{
    __shared__ unsigned short ldsAh[128][64];
    __shared__ unsigned short ldsAl[128][64];
    __shared__ unsigned short ldsBh[128][64];
    __shared__ unsigned short ldsBl[128][64];

    const int t    = threadIdx.x;
    const int lane = t & 63;
    const int wave = t >> 6;
    const int row0 = blockIdx.y * 128;
    const int n0g  = blockIdx.x * 128;

    const int srow = t >> 3;
    const int g    = (t & 7) ^ (srow & 7);
    const unsigned short *sAh[4], *sAl[4], *sBh[4], *sBl[4];
#pragma unroll
    for (int q = 0; q < 4; ++q) {
        const size_t ra = (size_t)(row0 + q * 32 + srow) * KIN + g * 8;
        const size_t rb = (size_t)(n0g + q * 32 + srow) * KIN + g * 8;
        sAh[q] = Ah + ra; sAl[q] = Al + ra;
        sBh[q] = BhT + rb; sBl[q] = BlT + rb;
    }

    const int grp = lane >> 4;
    int offA[2][4], offB[2][4];
#pragma unroll
    for (int ks = 0; ks < 2; ++ks)
#pragma unroll
        for (int m = 0; m < 4; ++m) {
            const int rA = ((wave >> 1) * 64) + m * 16 + (lane & 15);
            const int rB = ((wave & 1) * 64) + m * 16 + (lane & 15);
            const int c  = ks * 4 + grp;
            offA[ks][m] = rA * 128 + (((c ^ (rA & 7)) & 7) << 4);
            offB[ks][m] = rB * 128 + (((c ^ (rB & 7)) & 7) << 4);
        }

    floatx4 acc[4][4];
#pragma unroll
    for (int m = 0; m < 4; ++m)
#pragma unroll
        for (int n = 0; n < 4; ++n) acc[m][n] = (floatx4){0.f, 0.f, 0.f, 0.f};

    const char* lAh = (const char*)&ldsAh[0][0];
    const char* lAl = (const char*)&ldsAl[0][0];
    const char* lBh = (const char*)&ldsBh[0][0];
    const char* lBl = (const char*)&ldsBl[0][0];

    for (int kt = 0; kt < KIN / 64; ++kt) {
        const int k0 = kt * 64;
        __syncthreads();
#pragma unroll
        for (int q = 0; q < 4; ++q) {
            const int dst = q * 4096 + wave * 1024;
            __builtin_amdgcn_global_load_lds(AS1U(sAh[q] + k0), AS3U((char*)lAh + dst), 16, 0, 0);
            __builtin_amdgcn_global_load_lds(AS1U(sAl[q] + k0), AS3U((char*)lAl + dst), 16, 0, 0);
            __builtin_amdgcn_global_load_lds(AS1U(sBh[q] + k0), AS3U((char*)lBh + dst), 16, 0, 0);
            __builtin_amdgcn_global_load_lds(AS1U(sBl[q] + k0), AS3U((char*)lBl + dst), 16, 0, 0);
        }
        __syncthreads();
#pragma unroll
        for (int ks = 0; ks < 2; ++ks) {
            half8 ah[4], al[4], bh[4], bl[4];
#pragma unroll
            for (int m = 0; m < 4; ++m) {
                ah[m] = *(const half8*)(lAh + offA[ks][m]);
                al[m] = *(const half8*)(lAl + offA[ks][m]);
            }
#pragma unroll
            for (int n = 0; n < 4; ++n) {
                bh[n] = *(const half8*)(lBh + offB[ks][n]);
                bl[n] = *(const half8*)(lBl + offB[ks][n]);
            }
#pragma unroll
            for (int m = 0; m < 4; ++m)
#pragma unroll
                for (int n = 0; n < 4; ++n) {
                    acc[m][n] = __builtin_amdgcn_mfma_f32_16x16x32_f16(ah[m], bh[n], acc[m][n], 0, 0, 0);
                    acc[m][n] = __builtin_amdgcn_mfma_f32_16x16x32_f16(ah[m], bl[n], acc[m][n], 0, 0, 0);
                    acc[m][n] = __builtin_amdgcn_mfma_f32_16x16x32_f16(al[m], bh[n], acc[m][n], 0, 0, 0);
                }
        }
    }

    const int wr = wave >> 1, wc = wave & 1;
#pragma unroll
    for (int n = 0; n < 4; ++n) {
        const int col  = n0g + wc * 64 + n * 16 + (lane & 15);
        const float bias = bs[col];
#pragma unroll
        for (int m = 0; m < 4; ++m) {
            const int rbase = row0 + wr * 64 + m * 16 + (lane >> 4) * 4;
#pragma unroll
            for (int reg = 0; reg < 4; ++reg) {
                const float o = gelu_f(acc[m][n][reg] * (1.0f / 1024.0f) + bias);
                h[(size_t)(rbase + reg) * DM + col]   = o;
                hbf[(size_t)(rbase + reg) * DM + col] = f2bf(o);
            }
        }
    }
}

// ---------------- W_experts fp32 [e][k][n] -> bf16 transposed [e][n][k] ----------------
__global__ __launch_bounds__(256) void k_wt_bf16(
    const float* __restrict__ We, unsigned short* __restrict__ WeT)
{
    __shared__ float s[32][33];
    const int e  = blockIdx.z;
    const int k0 = blockIdx.y * 32, n0 = blockIdx.x * 32;
    const int c  = threadIdx.x & 31, r = threadIdx.x >> 5;
    const float* W = We + ((size_t)e << 20);
#pragma unroll
    for (int p = 0; p < 4; ++p) {
        const int k = r + p * 8;
        s[k][c] = W[(size_t)(k0 + k) * DM + n0 + c];
    }
    __syncthreads();
#pragma unroll
    for (int p = 0; p < 4; ++p) {
        const int n = r + p * 8;
        WeT[((size_t)e << 20) + (size_t)(n0 + n) * DM + k0 + c] = f2bf(s[c][n]);
    }
}

// ---------------- gate top-2: fp32 exact, NO atomics ----------------
__global__ __launch_bounds__(256) void k_gate_topk(
    const float* __restrict__ h, const float* __restrict__ Wg,
    const float* __restrict__ bg, int* __restrict__ eidx,
    float2* __restrict__ w01)
{
    const int lane = threadIdx.x & 63;
    const int wv   = threadIdx.x >> 6;
    const int tok  = blockIdx.x * 4 + wv;
    const float* hr = h + (size_t)tok * DM;
    float acc[NEXP];
#pragma unroll
    for (int e = 0; e < NEXP; ++e) acc[e] = 0.f;
    for (int j = 0; j < DM / 64; ++j) {
        const float hv = hr[lane + 64 * j];
        const float* wr = Wg + (size_t)(lane + 64 * j) * NEXP;
#pragma unroll
        for (int e = 0; e < NEXP; ++e) acc[e] = fmaf(hv, wr[e], acc[e]);
    }
#pragma unroll
    for (int off = 32; off > 0; off >>= 1) {
#pragma unroll
        for (int e = 0; e < NEXP; ++e) acc[e] += __shfl_xor(acc[e], off, 64);
    }
    if (lane == 0) {
        float lg[NEXP];
        float mx = -1e30f;
#pragma unroll
        for (int e = 0; e < NEXP; ++e) { lg[e] = acc[e] + bg[e]; mx = fmaxf(mx, lg[e]); }
        float p[NEXP]; float s = 0.f;
#pragma unroll
        for (int e = 0; e < NEXP; ++e) { p[e] = expf(lg[e] - mx); s += p[e]; }
        const float inv = 1.f / s;
        int i0 = 0;
#pragma unroll
        for (int e = 1; e < NEXP; ++e) if (p[e] > p[i0]) i0 = e;
        int i1 = (i0 == 0) ? 1 : 0;
#pragma unroll
        for (int e = 0; e < NEXP; ++e) if (e != i0 && p[e] > p[i1]) i1 = e;
        eidx[tok] = i0 | (i1 << 8);
        w01[tok]  = make_float2(p[i0] * inv, p[i1] * inv);
    }
}

// ---------------- bucketize: block-aggregated (512 global atomics total) ----------------
__global__ __launch_bounds__(256) void k_bucket(
    const int* __restrict__ eidx, const float2* __restrict__ w01,
    int* __restrict__ counts, int* __restrict__ btok, float* __restrict__ bwgt)
{
    __shared__ int lcnt[NEXP], lbase[NEXP];
    const int tid = threadIdx.x;
    const int tok = blockIdx.x * 256 + tid;
    if (tid < NEXP) lcnt[tid] = 0;
    __syncthreads();
    const int ee = eidx[tok];
    const float2 w = w01[tok];
    const int e0 = ee & 0xff, e1 = ee >> 8;
    const int l0 = atomicAdd(&lcnt[e0], 1);
    const int l1 = atomicAdd(&lcnt[e1], 1);
    __syncthreads();
    if (tid < NEXP) lbase[tid] = atomicAdd(&counts[tid], lcnt[tid]);
    __syncthreads();
    const int s0 = lbase[e0] + l0;
    btok[e0 * NB_TOK + s0] = tok;  bwgt[e0 * NB_TOK + s0] = w.x;
    const int s1 = lbase[e1] + l1;
    btok[e1 * NB_TOK + s1] = tok;  bwgt[e1 * NB_TOK + s1] = w.y;
}

// ---------------- expert GEMM: bf16 MFMA, gathered rows, atomic epilogue ----------------
__global__ __launch_bounds__(256) void k_expert_mfma(
    const unsigned short* __restrict__ hbf,
    const unsigned short* __restrict__ WeT,
    const float* __restrict__ bexp,
    const int* __restrict__ counts,
    const int* __restrict__ btok, const float* __restrict__ bwgt,
    float* __restrict__ out)
{
    const int e    = blockIdx.z;
    const int cnt  = counts[e];
    const int row0 = blockIdx.y * 128;
    if (row0 >= cnt) return;

    __shared__ unsigned short ldsA[128][64];
    __shared__ unsigned short ldsB[128][64];
    __shared__ int   sTok[128];
    __shared__ float sWt[128];

    const int t    = threadIdx.x;
    const int lane = t & 63;
    const int wave = t >> 6;

    if (t < 128) {
        const int idx = row0 + t;
        if (idx < cnt) { sTok[t] = btok[e * NB_TOK + idx]; sWt[t] = bwgt[e * NB_TOK + idx]; }
        else           { sTok[t] = -1;                     sWt[t] = 0.f; }
    }
    __syncthreads();

    const int srow = t >> 3;
    const int g    = (t & 7) ^ (srow & 7);
    const int n0g  = blockIdx.x * 128;
    const unsigned short* srcA[4];
    const unsigned short* srcB[4];
#pragma unroll
    for (int q = 0; q < 4; ++q) {
        int tk = sTok[q * 32 + srow];
        if (tk < 0) tk = 0;
        srcA[q] = hbf + (size_t)tk * DM + g * 8;
        srcB[q] = WeT + ((size_t)e << 20) + (size_t)(n0g + q * 32 + srow) * DM + g * 8;
    }

    const int grp = lane >> 4;
    int offA[2][4], offB[2][4];
#pragma unroll
    for (int ks = 0; ks < 2; ++ks)
#pragma unroll
        for (int m = 0; m < 4; ++m) {
            const int rA = ((wave >> 1) * 64) + m * 16 + (lane & 15);
            const int rB = ((wave & 1) * 64) + m * 16 + (lane & 15);
            const int c  = ks * 4 + grp;
            offA[ks][m] = rA * 128 + (((c ^ (rA & 7)) & 7) << 4);
            offB[ks][m] = rB * 128 + (((c ^ (rB & 7)) & 7) << 4);
        }

    floatx4 acc[4][4];
#pragma unroll
    for (int m = 0; m < 4; ++m)
#pragma unroll
        for (int n = 0; n < 4; ++n) acc[m][n] = (floatx4){0.f, 0.f, 0.f, 0.f};

    const char* lA = (const char*)&ldsA[0][0];
    const char* lB = (const char*)&ldsB[0][0];
    char* lAw = (char*)&ldsA[0][0];
    char* lBw = (char*)&ldsB[0][0];

    for (int kt = 0; kt < DM / 64; ++kt) {
        const int k0 = kt * 64;
        __syncthreads();
#pragma unroll
        for (int q = 0; q < 4; ++q) {
            __builtin_amdgcn_global_load_lds(AS1U(srcA[q] + k0), AS3U(lAw + q * 4096 + wave * 1024), 16, 0, 0);
            __builtin_amdgcn_global_load_lds(AS1U(srcB[q] + k0), AS3U(lBw + q * 4096 + wave * 1024), 16, 0, 0);
        }
        __syncthreads();
#pragma unroll
        for (int ks = 0; ks < 2; ++ks) {
            short8 av[4], bv[4];
#pragma unroll
            for (int m = 0; m < 4; ++m) av[m] = *(const short8*)(lA + offA[ks][m]);
#pragma unroll
            for (int n = 0; n < 4; ++n) bv[n] = *(const short8*)(lB + offB[ks][n]);
#pragma unroll
            for (int m = 0; m < 4; ++m)
#pragma unroll
                for (int n = 0; n < 4; ++n)
                    acc[m][n] = __builtin_amdgcn_mfma_f32_16x16x32_bf16(av[m], bv[n], acc[m][n], 0, 0, 0);
        }
    }

    const int wr = wave >> 1, wc = wave & 1;
#pragma unroll
    for (int n = 0; n < 4; ++n) {
        const int col  = n0g + wc * 64 + n * 16 + (lane & 15);
        const float bias = bexp[e * DM + col];
#pragma unroll
        for (int m = 0; m < 4; ++m) {
            const int rbase = wr * 64 + m * 16 + (lane >> 4) * 4;
#pragma unroll
            for (int reg = 0; reg < 4; ++reg) {
                const int r   = rbase + reg;
                const int tok = sTok[r];
                if (tok < 0) continue;
                const float v = gelu_f(acc[m][n][reg] + bias) * sWt[r];
                atomicAdd(out + (size_t)tok * DM + col, v);
            }
        }
    }
}

extern "C" void kernel_launch(void* const* d_in, const int* in_sizes, int n_in,
                              void* d_out, int out_size, void* d_ws, size_t ws_size,
                              hipStream_t stream)
{
    const float* f0 = (const float*)d_in[0];
    const float* f1 = (const float*)d_in[1];
    const float* f2 = (const float*)d_in[2];
    const float* Ws = (const float*)d_in[3];
    const float* bs = (const float*)d_in[4];
    const float* Wg = (const float*)d_in[5];
    const float* bg = (const float*)d_in[6];
    const float* We = (const float*)d_in[7];
    const float* be = (const float*)d_in[8];
    float* out = (float*)d_out;

    // ws layout (peak ~198MB):
    //  h   @ 0      (64MB) | hbf @ 64MB (32MB) | Ah @ 96MB (48MB, -> WeT alias)
    //  Al  @ 144MB  (48MB) | BhT @ 192MB (3MB, -> buckets alias) | BlT @ 195MB (3MB)
    char* base = (char*)d_ws;
    float*          h      = (float*)(base);
    unsigned short* hbf    = (unsigned short*)(base + 67108864);
    unsigned short* Ah     = (unsigned short*)(base + 100663296);
    unsigned short* WeT    = (unsigned short*)(base + 100663296);   // alias (after shared)
    unsigned short* Al     = (unsigned short*)(base + 150994944);
    unsigned short* BhT    = (unsigned short*)(base + 201326592);
    unsigned short* BlT    = (unsigned short*)(base + 204472320);
    int*            counts = (int*)(base + 201326592);              // alias BhT (after shared)
    int*            btok   = counts + 16;
    float*          bwgt   = (float*)(btok + NEXP * NB_TOK);
    int*            eidx   = (int*)(bwgt + NEXP * NB_TOK);
    float2*         w01    = (float2*)(eidx + NB_TOK);

    k_splitA<<<NB_TOK * (KIN / 4) / 256, 256, 0, stream>>>(f0, f1, f2, Ah, Al);
    k_splitB<<<dim3(DM / 32, KIN / 32), 256, 0, stream>>>(Ws, BhT, BlT);
    k_shared_mfma<<<dim3(DM / 128, NB_TOK / 128), 256, 0, stream>>>(Ah, Al, BhT, BlT, bs, h, hbf);

    hipMemsetAsync(counts, 0, 16 * sizeof(int), stream);
    k_gate_topk<<<NB_TOK / 4, 256, 0, stream>>>(h, Wg, bg, eidx, w01);
    k_bucket<<<NB_TOK / 256, 256, 0, stream>>>(eidx, w01, counts, btok, bwgt);

    k_wt_bf16<<<dim3(DM / 32, DM / 32, NEXP), 256, 0, stream>>>(We, WeT);

    hipMemsetAsync(d_out, 0, (size_t)NB_TOK * DM * sizeof(float), stream);
    k_expert_mfma<<<dim3(DM / 128, NB_TOK / 128, NEXP), 256, 0, stream>>>(hbf, WeT, be, counts, btok, bwgt, out);
}

// Round 6
// 526.457 us; speedup vs baseline: 3.9727x; 1.0005x over previous
//
#include <hip/hip_runtime.h>
#include <math.h>

#define NB_TOK 16384
#define DM     1024
#define NEXP   8
#define KIN    1536

typedef __attribute__((ext_vector_type(8))) short          short8;
typedef __attribute__((ext_vector_type(8))) unsigned short ushort8;
typedef __attribute__((ext_vector_type(4))) unsigned short ushort4v;
typedef __attribute__((ext_vector_type(8))) _Float16       half8;
typedef __attribute__((ext_vector_type(4))) float          floatx4;

#define AS1U(p) ((const __attribute__((address_space(1))) unsigned int*)(p))
#define AS3U(p) ((__attribute__((address_space(3))) unsigned int*)(p))

__device__ __forceinline__ float gelu_f(float x) {
    return 0.5f * x * (1.0f + erff(x * 0.70710678118654752440f));
}

__device__ __forceinline__ unsigned short f2bf(float x) {
    unsigned u = __float_as_uint(x);
    u = (u + 0x7FFF + ((u >> 16) & 1)) >> 16;   // RNE
    return (unsigned short)u;
}

__device__ __forceinline__ void split_h16(float x, unsigned short& hi, unsigned short& lo) {
    _Float16 h = (_Float16)x;
    float r = x - (float)h;
    _Float16 l = (_Float16)r;
    hi = *(unsigned short*)&h;
    lo = *(unsigned short*)&l;
}

// ---------------- feature split: concat fp32 -> fp16 hi/lo [tok][KIN], A scaled x4 ----------------
__global__ __launch_bounds__(256) void k_splitA(
    const float* __restrict__ f0, const float* __restrict__ f1,
    const float* __restrict__ f2, unsigned short* __restrict__ Ah,
    unsigned short* __restrict__ Al)
{
    const int i4  = blockIdx.x * 256 + threadIdx.x;
    const int tok = i4 / (KIN / 4);
    const int k   = (i4 % (KIN / 4)) * 4;
    const float* src; int ld, c;
    if (k < 768)       { src = f0; ld = 768; c = k; }
    else if (k < 1280) { src = f1; ld = 512; c = k - 768; }
    else               { src = f2; ld = 256; c = k - 1280; }
    const float4 v = *(const float4*)(src + (size_t)tok * ld + c);
    const float* vp = (const float*)&v;
    ushort4v hi, lo;
#pragma unroll
    for (int j = 0; j < 4; ++j) {
        unsigned short h, l;
        split_h16(vp[j] * 4.0f, h, l);
        hi[j] = h; lo[j] = l;
    }
    *(ushort4v*)(Ah + (size_t)tok * KIN + k) = hi;
    *(ushort4v*)(Al + (size_t)tok * KIN + k) = lo;
}

// ---------------- Ws fp32 [k][n] -> fp16 hi/lo transposed [n][k], scaled x256 ----------------
__global__ __launch_bounds__(256) void k_splitB(
    const float* __restrict__ Ws, unsigned short* __restrict__ BhT,
    unsigned short* __restrict__ BlT)
{
    __shared__ float s[32][33];
    const int n0 = blockIdx.x * 32, k0 = blockIdx.y * 32;
    const int c  = threadIdx.x & 31, r = threadIdx.x >> 5;
#pragma unroll
    for (int p = 0; p < 4; ++p)
        s[r + p * 8][c] = Ws[(size_t)(k0 + r + p * 8) * DM + n0 + c];
    __syncthreads();
#pragma unroll
    for (int p = 0; p < 4; ++p) {
        const int n = r + p * 8;
        unsigned short h, l;
        split_h16(s[c][n] * 256.0f, h, l);
        BhT[(size_t)(n0 + n) * KIN + k0 + c] = h;
        BlT[(size_t)(n0 + n) * KIN + k0 + c] = l;
    }
}

// ---------------- shared GEMM via fp16x2-split MFMA (3 products = fp32-grade) ----------------
__global__ __launch_bounds__(256) void k_shared_mfma(
    const unsigned short* __restrict__ Ah, const unsigned short* __restrict__ Al,
    const unsigned short* __restrict__ BhT, const unsigned short* __restrict__ BlT,
    const float* __restrict__ bs, float* __restrict__ h,
    unsigned short* __restrict__ hbf)
{
    __shared__ unsigned short ldsAh[128][64];
    __shared__ unsigned short ldsAl[128][64];
    __shared__ unsigned short ldsBh[128][64];
    __shared__ unsigned short ldsBl[128][64];

    const int t    = threadIdx.x;
    const int lane = t & 63;
    const int wave = t >> 6;
    const int row0 = blockIdx.y * 128;
    const int n0g  = blockIdx.x * 128;

    const int srow = t >> 3;
    const int g    = (t & 7) ^ (srow & 7);
    const unsigned short *sAh[4], *sAl[4], *sBh[4], *sBl[4];
#pragma unroll
    for (int q = 0; q < 4; ++q) {
        const size_t ra = (size_t)(row0 + q * 32 + srow) * KIN + g * 8;
        const size_t rb = (size_t)(n0g + q * 32 + srow) * KIN + g * 8;
        sAh[q] = Ah + ra; sAl[q] = Al + ra;
        sBh[q] = BhT + rb; sBl[q] = BlT + rb;
    }

    const int grp = lane >> 4;
    int offA[2][4], offB[2][4];
#pragma unroll
    for (int ks = 0; ks < 2; ++ks)
#pragma unroll
        for (int m = 0; m < 4; ++m) {
            const int rA = ((wave >> 1) * 64) + m * 16 + (lane & 15);
            const int rB = ((wave & 1) * 64) + m * 16 + (lane & 15);
            const int c  = ks * 4 + grp;
            offA[ks][m] = rA * 128 + (((c ^ (rA & 7)) & 7) << 4);
            offB[ks][m] = rB * 128 + (((c ^ (rB & 7)) & 7) << 4);
        }

    floatx4 acc[4][4];
#pragma unroll
    for (int m = 0; m < 4; ++m)
#pragma unroll
        for (int n = 0; n < 4; ++n) acc[m][n] = (floatx4){0.f, 0.f, 0.f, 0.f};

    const char* lAh = (const char*)&ldsAh[0][0];
    const char* lAl = (const char*)&ldsAl[0][0];
    const char* lBh = (const char*)&ldsBh[0][0];
    const char* lBl = (const char*)&ldsBl[0][0];

    for (int kt = 0; kt < KIN / 64; ++kt) {
        const int k0 = kt * 64;
        __syncthreads();
#pragma unroll
        for (int q = 0; q < 4; ++q) {
            const int dst = q * 4096 + wave * 1024;
            __builtin_amdgcn_global_load_lds(AS1U(sAh[q] + k0), AS3U((char*)lAh + dst), 16, 0, 0);
            __builtin_amdgcn_global_load_lds(AS1U(sAl[q] + k0), AS3U((char*)lAl + dst), 16, 0, 0);
            __builtin_amdgcn_global_load_lds(AS1U(sBh[q] + k0), AS3U((char*)lBh + dst), 16, 0, 0);
            __builtin_amdgcn_global_load_lds(AS1U(sBl[q] + k0), AS3U((char*)lBl + dst), 16, 0, 0);
        }
        __syncthreads();
#pragma unroll
        for (int ks = 0; ks < 2; ++ks) {
            half8 ah[4], al[4], bh[4], bl[4];
#pragma unroll
            for (int m = 0; m < 4; ++m) {
                ah[m] = *(const half8*)(lAh + offA[ks][m]);
                al[m] = *(const half8*)(lAl + offA[ks][m]);
            }
#pragma unroll
            for (int n = 0; n < 4; ++n) {
                bh[n] = *(const half8*)(lBh + offB[ks][n]);
                bl[n] = *(const half8*)(lBl + offB[ks][n]);
            }
#pragma unroll
            for (int m = 0; m < 4; ++m)
#pragma unroll
                for (int n = 0; n < 4; ++n) {
                    acc[m][n] = __builtin_amdgcn_mfma_f32_16x16x32_f16(ah[m], bh[n], acc[m][n], 0, 0, 0);
                    acc[m][n] = __builtin_amdgcn_mfma_f32_16x16x32_f16(ah[m], bl[n], acc[m][n], 0, 0, 0);
                    acc[m][n] = __builtin_amdgcn_mfma_f32_16x16x32_f16(al[m], bh[n], acc[m][n], 0, 0, 0);
                }
        }
    }

    const int wr = wave >> 1, wc = wave & 1;
#pragma unroll
    for (int n = 0; n < 4; ++n) {
        const int col  = n0g + wc * 64 + n * 16 + (lane & 15);
        const float bias = bs[col];
#pragma unroll
        for (int m = 0; m < 4; ++m) {
            const int rbase = row0 + wr * 64 + m * 16 + (lane >> 4) * 4;
#pragma unroll
            for (int reg = 0; reg < 4; ++reg) {
                const float o = gelu_f(acc[m][n][reg] * (1.0f / 1024.0f) + bias);
                h[(size_t)(rbase + reg) * DM + col]   = o;
                hbf[(size_t)(rbase + reg) * DM + col] = f2bf(o);
            }
        }
    }
}

// ---------------- W_experts fp32 [e][k][n] -> bf16 transposed [e][n][k] ----------------
__global__ __launch_bounds__(256) void k_wt_bf16(
    const float* __restrict__ We, unsigned short* __restrict__ WeT)
{
    __shared__ float s[32][33];
    const int e  = blockIdx.z;
    const int k0 = blockIdx.y * 32, n0 = blockIdx.x * 32;
    const int c  = threadIdx.x & 31, r = threadIdx.x >> 5;
    const float* W = We + ((size_t)e << 20);
#pragma unroll
    for (int p = 0; p < 4; ++p) {
        const int k = r + p * 8;
        s[k][c] = W[(size_t)(k0 + k) * DM + n0 + c];
    }
    __syncthreads();
#pragma unroll
    for (int p = 0; p < 4; ++p) {
        const int n = r + p * 8;
        WeT[((size_t)e << 20) + (size_t)(n0 + n) * DM + k0 + c] = f2bf(s[c][n]);
    }
}

// ---------------- gate top-2: fp32 exact, NO atomics ----------------
__global__ __launch_bounds__(256) void k_gate_topk(
    const float* __restrict__ h, const float* __restrict__ Wg,
    const float* __restrict__ bg, int* __restrict__ eidx,
    float2* __restrict__ w01)
{
    const int lane = threadIdx.x & 63;
    const int wv   = threadIdx.x >> 6;
    const int tok  = blockIdx.x * 4 + wv;
    const float* hr = h + (size_t)tok * DM;
    float acc[NEXP];
#pragma unroll
    for (int e = 0; e < NEXP; ++e) acc[e] = 0.f;
    for (int j = 0; j < DM / 64; ++j) {
        const float hv = hr[lane + 64 * j];
        const float* wr = Wg + (size_t)(lane + 64 * j) * NEXP;
#pragma unroll
        for (int e = 0; e < NEXP; ++e) acc[e] = fmaf(hv, wr[e], acc[e]);
    }
#pragma unroll
    for (int off = 32; off > 0; off >>= 1) {
#pragma unroll
        for (int e = 0; e < NEXP; ++e) acc[e] += __shfl_xor(acc[e], off, 64);
    }
    if (lane == 0) {
        float lg[NEXP];
        float mx = -1e30f;
#pragma unroll
        for (int e = 0; e < NEXP; ++e) { lg[e] = acc[e] + bg[e]; mx = fmaxf(mx, lg[e]); }
        float p[NEXP]; float s = 0.f;
#pragma unroll
        for (int e = 0; e < NEXP; ++e) { p[e] = expf(lg[e] - mx); s += p[e]; }
        const float inv = 1.f / s;
        int i0 = 0;
#pragma unroll
        for (int e = 1; e < NEXP; ++e) if (p[e] > p[i0]) i0 = e;
        int i1 = (i0 == 0) ? 1 : 0;
#pragma unroll
        for (int e = 0; e < NEXP; ++e) if (e != i0 && p[e] > p[i1]) i1 = e;
        eidx[tok] = i0 | (i1 << 8);
        w01[tok]  = make_float2(p[i0] * inv, p[i1] * inv);
    }
}

// ---------------- bucketize: block-aggregated (512 global atomics total) ----------------
__global__ __launch_bounds__(256) void k_bucket(
    const int* __restrict__ eidx, const float2* __restrict__ w01,
    int* __restrict__ counts, int* __restrict__ btok, float* __restrict__ bwgt)
{
    __shared__ int lcnt[NEXP], lbase[NEXP];
    const int tid = threadIdx.x;
    const int tok = blockIdx.x * 256 + tid;
    if (tid < NEXP) lcnt[tid] = 0;
    __syncthreads();
    const int ee = eidx[tok];
    const float2 w = w01[tok];
    const int e0 = ee & 0xff, e1 = ee >> 8;
    const int l0 = atomicAdd(&lcnt[e0], 1);
    const int l1 = atomicAdd(&lcnt[e1], 1);
    __syncthreads();
    if (tid < NEXP) lbase[tid] = atomicAdd(&counts[tid], lcnt[tid]);
    __syncthreads();
    const int s0 = lbase[e0] + l0;
    btok[e0 * NB_TOK + s0] = tok;  bwgt[e0 * NB_TOK + s0] = w.x;
    const int s1 = lbase[e1] + l1;
    btok[e1 * NB_TOK + s1] = tok;  bwgt[e1 * NB_TOK + s1] = w.y;
}

// ---------------- expert GEMM: bf16 MFMA, 2-phase double-buffered pipeline ----------------
#define EXP_STAGE(b, k0)                                                                              \
    {                                                                                                 \
        char* lAw = (char*)&ldsA[b][0][0];                                                            \
        char* lBw = (char*)&ldsB[b][0][0];                                                            \
        _Pragma("unroll")                                                                             \
        for (int q = 0; q < 4; ++q) {                                                                 \
            __builtin_amdgcn_global_load_lds(AS1U(srcA[q] + (k0)), AS3U(lAw + q * 4096 + wave * 1024), 16, 0, 0); \
            __builtin_amdgcn_global_load_lds(AS1U(srcB[q] + (k0)), AS3U(lBw + q * 4096 + wave * 1024), 16, 0, 0); \
        }                                                                                             \
    }

__global__ __launch_bounds__(256) void k_expert_mfma(
    const unsigned short* __restrict__ hbf,
    const unsigned short* __restrict__ WeT,
    const float* __restrict__ bexp,
    const int* __restrict__ counts,
    const int* __restrict__ btok, const float* __restrict__ bwgt,
    float* __restrict__ out)
{
    const int e    = blockIdx.z;
    const int cnt  = counts[e];
    const int row0 = blockIdx.y * 128;
    if (row0 >= cnt) return;

    __shared__ unsigned short ldsA[2][128][64];   // 32KB double-buffered
    __shared__ unsigned short ldsB[2][128][64];   // 32KB
    __shared__ int   sTok[128];
    __shared__ float sWt[128];

    const int t    = threadIdx.x;
    const int lane = t & 63;
    const int wave = t >> 6;

    if (t < 128) {
        const int idx = row0 + t;
        if (idx < cnt) { sTok[t] = btok[e * NB_TOK + idx]; sWt[t] = bwgt[e * NB_TOK + idx]; }
        else           { sTok[t] = -1;                     sWt[t] = 0.f; }
    }
    __syncthreads();

    const int srow = t >> 3;
    const int g    = (t & 7) ^ (srow & 7);
    const int n0g  = blockIdx.x * 128;
    const unsigned short* srcA[4];
    const unsigned short* srcB[4];
#pragma unroll
    for (int q = 0; q < 4; ++q) {
        int tk = sTok[q * 32 + srow];
        if (tk < 0) tk = 0;
        srcA[q] = hbf + (size_t)tk * DM + g * 8;
        srcB[q] = WeT + ((size_t)e << 20) + (size_t)(n0g + q * 32 + srow) * DM + g * 8;
    }

    const int grp = lane >> 4;
    int offA[2][4], offB[2][4];
#pragma unroll
    for (int ks = 0; ks < 2; ++ks)
#pragma unroll
        for (int m = 0; m < 4; ++m) {
            const int rA = ((wave >> 1) * 64) + m * 16 + (lane & 15);
            const int rB = ((wave & 1) * 64) + m * 16 + (lane & 15);
            const int c  = ks * 4 + grp;
            offA[ks][m] = rA * 128 + (((c ^ (rA & 7)) & 7) << 4);
            offB[ks][m] = rB * 128 + (((c ^ (rB & 7)) & 7) << 4);
        }

    floatx4 acc[4][4];
#pragma unroll
    for (int m = 0; m < 4; ++m)
#pragma unroll
        for (int n = 0; n < 4; ++n) acc[m][n] = (floatx4){0.f, 0.f, 0.f, 0.f};

    // prologue: fill buffer 0
    EXP_STAGE(0, 0);

    int buf = 0;
    for (int kt = 0; kt < DM / 64; ++kt) {
        // barrier drains vmcnt -> buf's loads (issued one full phase ago) are in LDS,
        // and all waves finished reading buf^1 last iteration.
        __syncthreads();
        if (kt + 1 < DM / 64) EXP_STAGE(buf ^ 1, (kt + 1) * 64);   // prefetch next tile, no wait
        const char* lA = (const char*)&ldsA[buf][0][0];
        const char* lB = (const char*)&ldsB[buf][0][0];
#pragma unroll
        for (int ks = 0; ks < 2; ++ks) {
            short8 av[4], bv[4];
#pragma unroll
            for (int m = 0; m < 4; ++m) av[m] = *(const short8*)(lA + offA[ks][m]);
#pragma unroll
            for (int n = 0; n < 4; ++n) bv[n] = *(const short8*)(lB + offB[ks][n]);
#pragma unroll
            for (int m = 0; m < 4; ++m)
#pragma unroll
                for (int n = 0; n < 4; ++n)
                    acc[m][n] = __builtin_amdgcn_mfma_f32_16x16x32_bf16(av[m], bv[n], acc[m][n], 0, 0, 0);
        }
        buf ^= 1;
    }

    const int wr = wave >> 1, wc = wave & 1;
#pragma unroll
    for (int n = 0; n < 4; ++n) {
        const int col  = n0g + wc * 64 + n * 16 + (lane & 15);
        const float bias = bexp[e * DM + col];
#pragma unroll
        for (int m = 0; m < 4; ++m) {
            const int rbase = wr * 64 + m * 16 + (lane >> 4) * 4;
#pragma unroll
            for (int reg = 0; reg < 4; ++reg) {
                const int r   = rbase + reg;
                const int tok = sTok[r];
                if (tok < 0) continue;
                const float v = gelu_f(acc[m][n][reg] + bias) * sWt[r];
                atomicAdd(out + (size_t)tok * DM + col, v);
            }
        }
    }
}

extern "C" void kernel_launch(void* const* d_in, const int* in_sizes, int n_in,
                              void* d_out, int out_size, void* d_ws, size_t ws_size,
                              hipStream_t stream)
{
    const float* f0 = (const float*)d_in[0];
    const float* f1 = (const float*)d_in[1];
    const float* f2 = (const float*)d_in[2];
    const float* Ws = (const float*)d_in[3];
    const float* bs = (const float*)d_in[4];
    const float* Wg = (const float*)d_in[5];
    const float* bg = (const float*)d_in[6];
    const float* We = (const float*)d_in[7];
    const float* be = (const float*)d_in[8];
    float* out = (float*)d_out;

    // ws layout (peak ~198MB):
    //  h   @ 0      (64MB) | hbf @ 64MB (32MB) | Ah @ 96MB (48MB, -> WeT alias)
    //  Al  @ 144MB  (48MB) | BhT @ 192MB (3MB, -> buckets alias) | BlT @ 195MB (3MB)
    char* base = (char*)d_ws;
    float*          h      = (float*)(base);
    unsigned short* hbf    = (unsigned short*)(base + 67108864);
    unsigned short* Ah     = (unsigned short*)(base + 100663296);
    unsigned short* WeT    = (unsigned short*)(base + 100663296);   // alias (after shared)
    unsigned short* Al     = (unsigned short*)(base + 150994944);
    unsigned short* BhT    = (unsigned short*)(base + 201326592);
    unsigned short* BlT    = (unsigned short*)(base + 204472320);
    int*            counts = (int*)(base + 201326592);              // alias BhT (after shared)
    int*            btok   = counts + 16;
    float*          bwgt   = (float*)(btok + NEXP * NB_TOK);
    int*            eidx   = (int*)(bwgt + NEXP * NB_TOK);
    float2*         w01    = (float2*)(eidx + NB_TOK);

    k_splitA<<<NB_TOK * (KIN / 4) / 256, 256, 0, stream>>>(f0, f1, f2, Ah, Al);
    k_splitB<<<dim3(DM / 32, KIN / 32), 256, 0, stream>>>(Ws, BhT, BlT);
    k_shared_mfma<<<dim3(DM / 128, NB_TOK / 128), 256, 0, stream>>>(Ah, Al, BhT, BlT, bs, h, hbf);

    hipMemsetAsync(counts, 0, 16 * sizeof(int), stream);
    k_gate_topk<<<NB_TOK / 4, 256, 0, stream>>>(h, Wg, bg, eidx, w01);
    k_bucket<<<NB_TOK / 256, 256, 0, stream>>>(eidx, w01, counts, btok, bwgt);

    k_wt_bf16<<<dim3(DM / 32, DM / 32, NEXP), 256, 0, stream>>>(We, WeT);

    hipMemsetAsync(d_out, 0, (size_t)NB_TOK * DM * sizeof(float), stream);
    k_expert_mfma<<<dim3(DM / 128, NB_TOK / 128, NEXP), 256, 0, stream>>>(hbf, WeT, be, counts, btok, bwgt, out);
}

// Round 7
// 479.462 us; speedup vs baseline: 4.3621x; 1.0980x over previous
//
#include <hip/hip_runtime.h>
#include <math.h>

#define NB_TOK 16384
#define DM     1024
#define NEXP   8
#define KIN    1536

typedef __attribute__((ext_vector_type(8))) short          short8;
typedef __attribute__((ext_vector_type(8))) unsigned short ushort8;
typedef __attribute__((ext_vector_type(4))) unsigned short ushort4v;
typedef __attribute__((ext_vector_type(8))) _Float16       half8;
typedef __attribute__((ext_vector_type(4))) float          floatx4;

#define AS1U(p) ((const __attribute__((address_space(1))) unsigned int*)(p))
#define AS3U(p) ((__attribute__((address_space(3))) unsigned int*)(p))

__device__ __forceinline__ float gelu_f(float x) {
    return 0.5f * x * (1.0f + erff(x * 0.70710678118654752440f));
}

__device__ __forceinline__ unsigned short f2bf(float x) {
    unsigned u = __float_as_uint(x);
    u = (u + 0x7FFF + ((u >> 16) & 1)) >> 16;   // RNE
    return (unsigned short)u;
}

__device__ __forceinline__ void split_h16(float x, unsigned short& hi, unsigned short& lo) {
    _Float16 h = (_Float16)x;
    float r = x - (float)h;
    _Float16 l = (_Float16)r;
    hi = *(unsigned short*)&h;
    lo = *(unsigned short*)&l;
}

// ---------------- feature split: concat fp32 -> fp16 hi/lo [tok][KIN], A scaled x4 ----------------
__global__ __launch_bounds__(256) void k_splitA(
    const float* __restrict__ f0, const float* __restrict__ f1,
    const float* __restrict__ f2, unsigned short* __restrict__ Ah,
    unsigned short* __restrict__ Al)
{
    const int i4  = blockIdx.x * 256 + threadIdx.x;
    const int tok = i4 / (KIN / 4);
    const int k   = (i4 % (KIN / 4)) * 4;
    const float* src; int ld, c;
    if (k < 768)       { src = f0; ld = 768; c = k; }
    else if (k < 1280) { src = f1; ld = 512; c = k - 768; }
    else               { src = f2; ld = 256; c = k - 1280; }
    const float4 v = *(const float4*)(src + (size_t)tok * ld + c);
    const float* vp = (const float*)&v;
    ushort4v hi, lo;
#pragma unroll
    for (int j = 0; j < 4; ++j) {
        unsigned short h, l;
        split_h16(vp[j] * 4.0f, h, l);
        hi[j] = h; lo[j] = l;
    }
    *(ushort4v*)(Ah + (size_t)tok * KIN + k) = hi;
    *(ushort4v*)(Al + (size_t)tok * KIN + k) = lo;
}

// ---------------- Ws fp32 [k][n] -> fp16 hi/lo transposed [n][k], scaled x256 ----------------
__global__ __launch_bounds__(256) void k_splitB(
    const float* __restrict__ Ws, unsigned short* __restrict__ BhT,
    unsigned short* __restrict__ BlT)
{
    __shared__ float s[32][33];
    const int n0 = blockIdx.x * 32, k0 = blockIdx.y * 32;
    const int c  = threadIdx.x & 31, r = threadIdx.x >> 5;
#pragma unroll
    for (int p = 0; p < 4; ++p)
        s[r + p * 8][c] = Ws[(size_t)(k0 + r + p * 8) * DM + n0 + c];
    __syncthreads();
#pragma unroll
    for (int p = 0; p < 4; ++p) {
        const int n = r + p * 8;
        unsigned short h, l;
        split_h16(s[c][n] * 256.0f, h, l);
        BhT[(size_t)(n0 + n) * KIN + k0 + c] = h;
        BlT[(size_t)(n0 + n) * KIN + k0 + c] = l;
    }
}

// ---------------- shared GEMM via fp16x2-split MFMA (3 products = fp32-grade) ----------------
__global__ __launch_bounds__(256) void k_shared_mfma(
    const unsigned short* __restrict__ Ah, const unsigned short* __restrict__ Al,
    const unsigned short* __restrict__ BhT, const unsigned short* __restrict__ BlT,
    const float* __restrict__ bs, float* __restrict__ h,
    unsigned short* __restrict__ hbf)
{
    __shared__ unsigned short ldsAh[128][64];
    __shared__ unsigned short ldsAl[128][64];
    __shared__ unsigned short ldsBh[128][64];
    __shared__ unsigned short ldsBl[128][64];

    const int t    = threadIdx.x;
    const int lane = t & 63;
    const int wave = t >> 6;
    const int row0 = blockIdx.y * 128;
    const int n0g  = blockIdx.x * 128;

    const int srow = t >> 3;
    const int g    = (t & 7) ^ (srow & 7);
    const unsigned short *sAh[4], *sAl[4], *sBh[4], *sBl[4];
#pragma unroll
    for (int q = 0; q < 4; ++q) {
        const size_t ra = (size_t)(row0 + q * 32 + srow) * KIN + g * 8;
        const size_t rb = (size_t)(n0g + q * 32 + srow) * KIN + g * 8;
        sAh[q] = Ah + ra; sAl[q] = Al + ra;
        sBh[q] = BhT + rb; sBl[q] = BlT + rb;
    }

    const int grp = lane >> 4;
    int offA[2][4], offB[2][4];
#pragma unroll
    for (int ks = 0; ks < 2; ++ks)
#pragma unroll
        for (int m = 0; m < 4; ++m) {
            const int rA = ((wave >> 1) * 64) + m * 16 + (lane & 15);
            const int rB = ((wave & 1) * 64) + m * 16 + (lane & 15);
            const int c  = ks * 4 + grp;
            offA[ks][m] = rA * 128 + (((c ^ (rA & 7)) & 7) << 4);
            offB[ks][m] = rB * 128 + (((c ^ (rB & 7)) & 7) << 4);
        }

    floatx4 acc[4][4];
#pragma unroll
    for (int m = 0; m < 4; ++m)
#pragma unroll
        for (int n = 0; n < 4; ++n) acc[m][n] = (floatx4){0.f, 0.f, 0.f, 0.f};

    const char* lAh = (const char*)&ldsAh[0][0];
    const char* lAl = (const char*)&ldsAl[0][0];
    const char* lBh = (const char*)&ldsBh[0][0];
    const char* lBl = (const char*)&ldsBl[0][0];

    for (int kt = 0; kt < KIN / 64; ++kt) {
        const int k0 = kt * 64;
        __syncthreads();
#pragma unroll
        for (int q = 0; q < 4; ++q) {
            const int dst = q * 4096 + wave * 1024;
            __builtin_amdgcn_global_load_lds(AS1U(sAh[q] + k0), AS3U((char*)lAh + dst), 16, 0, 0);
            __builtin_amdgcn_global_load_lds(AS1U(sAl[q] + k0), AS3U((char*)lAl + dst), 16, 0, 0);
            __builtin_amdgcn_global_load_lds(AS1U(sBh[q] + k0), AS3U((char*)lBh + dst), 16, 0, 0);
            __builtin_amdgcn_global_load_lds(AS1U(sBl[q] + k0), AS3U((char*)lBl + dst), 16, 0, 0);
        }
        __syncthreads();
#pragma unroll
        for (int ks = 0; ks < 2; ++ks) {
            half8 ah[4], al[4], bh[4], bl[4];
#pragma unroll
            for (int m = 0; m < 4; ++m) {
                ah[m] = *(const half8*)(lAh + offA[ks][m]);
                al[m] = *(const half8*)(lAl + offA[ks][m]);
            }
#pragma unroll
            for (int n = 0; n < 4; ++n) {
                bh[n] = *(const half8*)(lBh + offB[ks][n]);
                bl[n] = *(const half8*)(lBl + offB[ks][n]);
            }
#pragma unroll
            for (int m = 0; m < 4; ++m)
#pragma unroll
                for (int n = 0; n < 4; ++n) {
                    acc[m][n] = __builtin_amdgcn_mfma_f32_16x16x32_f16(ah[m], bh[n], acc[m][n], 0, 0, 0);
                    acc[m][n] = __builtin_amdgcn_mfma_f32_16x16x32_f16(ah[m], bl[n], acc[m][n], 0, 0, 0);
                    acc[m][n] = __builtin_amdgcn_mfma_f32_16x16x32_f16(al[m], bh[n], acc[m][n], 0, 0, 0);
                }
        }
    }

    const int wr = wave >> 1, wc = wave & 1;
#pragma unroll
    for (int n = 0; n < 4; ++n) {
        const int col  = n0g + wc * 64 + n * 16 + (lane & 15);
        const float bias = bs[col];
#pragma unroll
        for (int m = 0; m < 4; ++m) {
            const int rbase = row0 + wr * 64 + m * 16 + (lane >> 4) * 4;
#pragma unroll
            for (int reg = 0; reg < 4; ++reg) {
                const float o = gelu_f(acc[m][n][reg] * (1.0f / 1024.0f) + bias);
                h[(size_t)(rbase + reg) * DM + col]   = o;
                hbf[(size_t)(rbase + reg) * DM + col] = f2bf(o);
            }
        }
    }
}

// ---------------- W_experts fp32 [e][k][n] -> bf16 transposed [e][n][k] ----------------
__global__ __launch_bounds__(256) void k_wt_bf16(
    const float* __restrict__ We, unsigned short* __restrict__ WeT)
{
    __shared__ float s[32][33];
    const int e  = blockIdx.z;
    const int k0 = blockIdx.y * 32, n0 = blockIdx.x * 32;
    const int c  = threadIdx.x & 31, r = threadIdx.x >> 5;
    const float* W = We + ((size_t)e << 20);
#pragma unroll
    for (int p = 0; p < 4; ++p) {
        const int k = r + p * 8;
        s[k][c] = W[(size_t)(k0 + k) * DM + n0 + c];
    }
    __syncthreads();
#pragma unroll
    for (int p = 0; p < 4; ++p) {
        const int n = r + p * 8;
        WeT[((size_t)e << 20) + (size_t)(n0 + n) * DM + k0 + c] = f2bf(s[c][n]);
    }
}

// ---------------- gate top-2: fp32 exact, NO atomics ----------------
__global__ __launch_bounds__(256) void k_gate_topk(
    const float* __restrict__ h, const float* __restrict__ Wg,
    const float* __restrict__ bg, int* __restrict__ eidx,
    float2* __restrict__ w01)
{
    const int lane = threadIdx.x & 63;
    const int wv   = threadIdx.x >> 6;
    const int tok  = blockIdx.x * 4 + wv;
    const float* hr = h + (size_t)tok * DM;
    float acc[NEXP];
#pragma unroll
    for (int e = 0; e < NEXP; ++e) acc[e] = 0.f;
    for (int j = 0; j < DM / 64; ++j) {
        const float hv = hr[lane + 64 * j];
        const float* wr = Wg + (size_t)(lane + 64 * j) * NEXP;
#pragma unroll
        for (int e = 0; e < NEXP; ++e) acc[e] = fmaf(hv, wr[e], acc[e]);
    }
#pragma unroll
    for (int off = 32; off > 0; off >>= 1) {
#pragma unroll
        for (int e = 0; e < NEXP; ++e) acc[e] += __shfl_xor(acc[e], off, 64);
    }
    if (lane == 0) {
        float lg[NEXP];
        float mx = -1e30f;
#pragma unroll
        for (int e = 0; e < NEXP; ++e) { lg[e] = acc[e] + bg[e]; mx = fmaxf(mx, lg[e]); }
        float p[NEXP]; float s = 0.f;
#pragma unroll
        for (int e = 0; e < NEXP; ++e) { p[e] = expf(lg[e] - mx); s += p[e]; }
        const float inv = 1.f / s;
        int i0 = 0;
#pragma unroll
        for (int e = 1; e < NEXP; ++e) if (p[e] > p[i0]) i0 = e;
        int i1 = (i0 == 0) ? 1 : 0;
#pragma unroll
        for (int e = 0; e < NEXP; ++e) if (e != i0 && p[e] > p[i1]) i1 = e;
        eidx[tok] = i0 | (i1 << 8);
        w01[tok]  = make_float2(p[i0] * inv, p[i1] * inv);
    }
}

// ---------------- bucketize: block-aggregated; also records per-token slots ----------------
__global__ __launch_bounds__(256) void k_bucket(
    const int* __restrict__ eidx, const float2* __restrict__ w01,
    int* __restrict__ counts, int* __restrict__ btok, float* __restrict__ bwgt,
    int2* __restrict__ tokslot)
{
    __shared__ int lcnt[NEXP], lbase[NEXP];
    const int tid = threadIdx.x;
    const int tok = blockIdx.x * 256 + tid;
    if (tid < NEXP) lcnt[tid] = 0;
    __syncthreads();
    const int ee = eidx[tok];
    const float2 w = w01[tok];
    const int e0 = ee & 0xff, e1 = ee >> 8;
    const int l0 = atomicAdd(&lcnt[e0], 1);
    const int l1 = atomicAdd(&lcnt[e1], 1);
    __syncthreads();
    if (tid < NEXP) lbase[tid] = atomicAdd(&counts[tid], lcnt[tid]);
    __syncthreads();
    const int s0 = lbase[e0] + l0;
    btok[e0 * NB_TOK + s0] = tok;  bwgt[e0 * NB_TOK + s0] = w.x;
    const int s1 = lbase[e1] + l1;
    btok[e1 * NB_TOK + s1] = tok;  bwgt[e1 * NB_TOK + s1] = w.y;
    tokslot[tok] = make_int2((e0 << 16) | s0, (e1 << 16) | s1);
}

// ---------------- exclusive prefix of counts -> compact stage bases ----------------
__global__ void k_prefix(const int* __restrict__ counts, int* __restrict__ basep)
{
    if (threadIdx.x == 0) {
        int r = 0;
#pragma unroll
        for (int e = 0; e < NEXP; ++e) { basep[e] = r; r += counts[e]; }
    }
}

// ---------------- expert GEMM: bf16 MFMA, 2-phase dbuf, STAGED epilogue (no atomics) ----------------
#define EXP_STAGE(b, k0)                                                                              \
    {                                                                                                 \
        char* lAw = (char*)&ldsA[b][0][0];                                                            \
        char* lBw = (char*)&ldsB[b][0][0];                                                            \
        _Pragma("unroll")                                                                             \
        for (int q = 0; q < 4; ++q) {                                                                 \
            __builtin_amdgcn_global_load_lds(AS1U(srcA[q] + (k0)), AS3U(lAw + q * 4096 + wave * 1024), 16, 0, 0); \
            __builtin_amdgcn_global_load_lds(AS1U(srcB[q] + (k0)), AS3U(lBw + q * 4096 + wave * 1024), 16, 0, 0); \
        }                                                                                             \
    }

__global__ __launch_bounds__(256) void k_expert_mfma(
    const unsigned short* __restrict__ hbf,
    const unsigned short* __restrict__ WeT,
    const float* __restrict__ bexp,
    const int* __restrict__ counts, const int* __restrict__ basep,
    const int* __restrict__ btok, const float* __restrict__ bwgt,
    float* __restrict__ stage)
{
    const int e    = blockIdx.z;
    const int cnt  = counts[e];
    const int row0 = blockIdx.y * 128;
    if (row0 >= cnt) return;
    const int gb   = basep[e];

    __shared__ unsigned short ldsA[2][128][64];
    __shared__ unsigned short ldsB[2][128][64];
    __shared__ int   sTok[128];
    __shared__ float sWt[128];

    const int t    = threadIdx.x;
    const int lane = t & 63;
    const int wave = t >> 6;

    if (t < 128) {
        const int idx = row0 + t;
        if (idx < cnt) { sTok[t] = btok[e * NB_TOK + idx]; sWt[t] = bwgt[e * NB_TOK + idx]; }
        else           { sTok[t] = -1;                     sWt[t] = 0.f; }
    }
    __syncthreads();

    const int srow = t >> 3;
    const int g    = (t & 7) ^ (srow & 7);
    const int n0g  = blockIdx.x * 128;
    const unsigned short* srcA[4];
    const unsigned short* srcB[4];
#pragma unroll
    for (int q = 0; q < 4; ++q) {
        int tk = sTok[q * 32 + srow];
        if (tk < 0) tk = 0;
        srcA[q] = hbf + (size_t)tk * DM + g * 8;
        srcB[q] = WeT + ((size_t)e << 20) + (size_t)(n0g + q * 32 + srow) * DM + g * 8;
    }

    const int grp = lane >> 4;
    int offA[2][4], offB[2][4];
#pragma unroll
    for (int ks = 0; ks < 2; ++ks)
#pragma unroll
        for (int m = 0; m < 4; ++m) {
            const int rA = ((wave >> 1) * 64) + m * 16 + (lane & 15);
            const int rB = ((wave & 1) * 64) + m * 16 + (lane & 15);
            const int c  = ks * 4 + grp;
            offA[ks][m] = rA * 128 + (((c ^ (rA & 7)) & 7) << 4);
            offB[ks][m] = rB * 128 + (((c ^ (rB & 7)) & 7) << 4);
        }

    floatx4 acc[4][4];
#pragma unroll
    for (int m = 0; m < 4; ++m)
#pragma unroll
        for (int n = 0; n < 4; ++n) acc[m][n] = (floatx4){0.f, 0.f, 0.f, 0.f};

    EXP_STAGE(0, 0);

    int buf = 0;
    for (int kt = 0; kt < DM / 64; ++kt) {
        __syncthreads();
        if (kt + 1 < DM / 64) EXP_STAGE(buf ^ 1, (kt + 1) * 64);
        const char* lA = (const char*)&ldsA[buf][0][0];
        const char* lB = (const char*)&ldsB[buf][0][0];
#pragma unroll
        for (int ks = 0; ks < 2; ++ks) {
            short8 av[4], bv[4];
#pragma unroll
            for (int m = 0; m < 4; ++m) av[m] = *(const short8*)(lA + offA[ks][m]);
#pragma unroll
            for (int n = 0; n < 4; ++n) bv[n] = *(const short8*)(lB + offB[ks][n]);
#pragma unroll
            for (int m = 0; m < 4; ++m)
#pragma unroll
                for (int n = 0; n < 4; ++n)
                    acc[m][n] = __builtin_amdgcn_mfma_f32_16x16x32_bf16(av[m], bv[n], acc[m][n], 0, 0, 0);
        }
        buf ^= 1;
    }

    // staged epilogue: plain coalesced stores, no atomics
    const int wr = wave >> 1, wc = wave & 1;
#pragma unroll
    for (int n = 0; n < 4; ++n) {
        const int col  = n0g + wc * 64 + n * 16 + (lane & 15);
        const float bias = bexp[e * DM + col];
#pragma unroll
        for (int m = 0; m < 4; ++m) {
            const int rbase = wr * 64 + m * 16 + (lane >> 4) * 4;
#pragma unroll
            for (int reg = 0; reg < 4; ++reg) {
                const int r = rbase + reg;
                if (sTok[r] < 0) continue;
                const float v = gelu_f(acc[m][n][reg] + bias) * sWt[r];
                stage[(size_t)(gb + row0 + r) * DM + col] = v;
            }
        }
    }
}

// ---------------- combine: out[tok] = stage[slot0] + stage[slot1] ----------------
__global__ __launch_bounds__(256) void k_combine(
    const float* __restrict__ stage, const int2* __restrict__ tokslot,
    const int* __restrict__ basep, float* __restrict__ out)
{
    const int tok = blockIdx.x;
    const int c   = threadIdx.x * 4;
    const int2 ts = tokslot[tok];
    const int g0 = basep[ts.x >> 16] + (ts.x & 0xFFFF);
    const int g1 = basep[ts.y >> 16] + (ts.y & 0xFFFF);
    const float4 a = *(const float4*)(stage + (size_t)g0 * DM + c);
    const float4 b = *(const float4*)(stage + (size_t)g1 * DM + c);
    float4 o;
    o.x = a.x + b.x; o.y = a.y + b.y; o.z = a.z + b.z; o.w = a.w + b.w;
    *(float4*)(out + (size_t)tok * DM + c) = o;
}

extern "C" void kernel_launch(void* const* d_in, const int* in_sizes, int n_in,
                              void* d_out, int out_size, void* d_ws, size_t ws_size,
                              hipStream_t stream)
{
    const float* f0 = (const float*)d_in[0];
    const float* f1 = (const float*)d_in[1];
    const float* f2 = (const float*)d_in[2];
    const float* Ws = (const float*)d_in[3];
    const float* bs = (const float*)d_in[4];
    const float* Wg = (const float*)d_in[5];
    const float* bg = (const float*)d_in[6];
    const float* We = (const float*)d_in[7];
    const float* be = (const float*)d_in[8];
    float* out = (float*)d_out;

    // ws layout, peak 198MB (lifetimes: step numbers in comments):
    //  Ah     @ 0      48MB  [1-3]   <- WeT (16MB, [7-8]) aliases @0; smalls (@16MB, [4-9]) alias
    //  Al     @ 48MB   48MB  [1-3]
    //  BhT    @ 96MB    3MB  [2-3]
    //  BlT    @ 99MB    3MB  [2-3]
    //  h      @ 102MB  64MB  [3-4]
    //  stage  @ 34MB  128MB  [8-9]   (overlays dead Ah-tail/Al/BhT/BlT/h-head)
    //  hbf    @ 166MB  32MB  [3-8]
    const size_t MB = 1048576ULL;
    char* base = (char*)d_ws;
    unsigned short* Ah   = (unsigned short*)(base);
    unsigned short* WeT  = (unsigned short*)(base);            // alias, used after Ah is dead
    unsigned short* Al   = (unsigned short*)(base + 48 * MB);
    unsigned short* BhT  = (unsigned short*)(base + 96 * MB);
    unsigned short* BlT  = (unsigned short*)(base + 99 * MB);
    float*          h    = (float*)(base + 102 * MB);
    float*          stage= (float*)(base + 34 * MB);
    unsigned short* hbf  = (unsigned short*)(base + 166 * MB);
    int*    counts  = (int*)(base + 16 * MB);
    int*    basep   = counts + 16;
    int*    btok    = counts + 64;
    float*  bwgt    = (float*)(btok + NEXP * NB_TOK);
    int*    eidx    = (int*)(bwgt + NEXP * NB_TOK);
    float2* w01     = (float2*)(eidx + NB_TOK);
    int2*   tokslot = (int2*)(w01 + NB_TOK);

    k_splitA<<<NB_TOK * (KIN / 4) / 256, 256, 0, stream>>>(f0, f1, f2, Ah, Al);          // 1
    k_splitB<<<dim3(DM / 32, KIN / 32), 256, 0, stream>>>(Ws, BhT, BlT);                 // 2
    k_shared_mfma<<<dim3(DM / 128, NB_TOK / 128), 256, 0, stream>>>(Ah, Al, BhT, BlT, bs, h, hbf); // 3

    hipMemsetAsync(counts, 0, 16 * sizeof(int), stream);
    k_gate_topk<<<NB_TOK / 4, 256, 0, stream>>>(h, Wg, bg, eidx, w01);                   // 4
    k_bucket<<<NB_TOK / 256, 256, 0, stream>>>(eidx, w01, counts, btok, bwgt, tokslot);  // 5
    k_prefix<<<1, 64, 0, stream>>>(counts, basep);                                       // 6

    k_wt_bf16<<<dim3(DM / 32, DM / 32, NEXP), 256, 0, stream>>>(We, WeT);                // 7

    k_expert_mfma<<<dim3(DM / 128, NB_TOK / 128, NEXP), 256, 0, stream>>>(               // 8
        hbf, WeT, be, counts, basep, btok, bwgt, stage);
    k_combine<<<NB_TOK, 256, 0, stream>>>(stage, tokslot, basep, out);                   // 9
}